// Round 15
// baseline (214.578 us; speedup 1.0000x reference)
//
#include <hip/hip_runtime.h>
#include <cstdint>

#define DEVI __device__ __forceinline__

constexpr int Bc = 4, Lc = 1024, DMc = 1024, Hc = 16, TDc = 8, Kc = 8, Dc = 64;
constexpr int NBL = Bc * Lc;               // 4096
constexpr int PAR = Hc * Dc * TDc * Kc;    // 65536 per param array

using f16x8 = __attribute__((ext_vector_type(8))) _Float16;
using f16x4 = __attribute__((ext_vector_type(4))) _Float16;
using s16x8 = __attribute__((ext_vector_type(8))) short;
using s16x4 = __attribute__((ext_vector_type(4))) short;
using f32x4 = __attribute__((ext_vector_type(4))) float;
using f32x2 = __attribute__((ext_vector_type(2))) float;

DEVI unsigned short f2bf(float x){
  union { float f; unsigned u; } v; v.f = x;
  return (unsigned short)((v.u + 0x7fffu + ((v.u >> 16) & 1u)) >> 16);
}

// packed f32x2 -> 2x bf16 in one v_cvt_pk_bf16_f32 (dst.lo = src0, RNE) [T12/m240]
DEVI unsigned cvtpk_bf16(float lo, float hi){
  unsigned r;
  asm("v_cvt_pk_bf16_f32 %0, %1, %2" : "=v"(r) : "v"(lo), "v"(hi));
  return r;
}

// LDS swizzle — ON (write/read pairs audited r0; k12 pre-swizzles K/V global layout).
#define SWZ_ON 1
DEVI int swz(int row, int unit){
#if SWZ_ON
  return unit ^ (row & 7);
#else
  (void)row; return unit;
#endif
}

// ---------------- K0: precompute alpha = sqrt(log2e/2)/sigma ; WO -> bf16 ----
__global__ __launch_bounds__(256) void k0_alpha(
    const float* __restrict__ sQ, const float* __restrict__ sK, const float* __restrict__ sV,
    float* __restrict__ aQ, float* __restrict__ aK, float* __restrict__ aV)
{
  int i = blockIdx.x * 256 + threadIdx.x;
  if (i < PAR){
    const float c = 0.8493218002880191f; // sqrt(log2(e)/2)
    aQ[i] = c / sQ[i];
    aK[i] = c / sK[i];
    aV[i] = c / sV[i];
  }
}

__global__ __launch_bounds__(256) void k0_wo(const float* __restrict__ WO, unsigned short* __restrict__ WOb)
{
  int i = blockIdx.x * 256 + threadIdx.x;
  if (i < DMc * DMc) WOb[i] = f2bf(WO[i]);
}

// W split: [p][h][f][d] transposed f16 hi/lo; W_Q pre-scaled (scale is linear).
__global__ __launch_bounds__(256) void k0_wsplit(
    const float* __restrict__ WQ, const float* __restrict__ WK, const float* __restrict__ WV,
    _Float16* __restrict__ Whi, _Float16* __restrict__ Wlo)
{
  int i = blockIdx.x * 256 + threadIdx.x;
  if (i >= 3 * Hc * 64 * 64) return;
  const int d = i & 63, f = (i >> 6) & 63, h = (i >> 12) & 15, p = i >> 16;
  const float* W = (p == 0) ? WQ : (p == 1) ? WK : WV;
  float v = W[((size_t)h * 64 + d) * 64 + f];
  if (p == 0) v *= 0.18033688011112042f;   // log2(e)/sqrt(D)
  const _Float16 hi = (_Float16)v;
  Whi[i] = hi;
  Wlo[i] = (_Float16)(v - (float)hi);
}

// ---------------- K12: FUSED gaussian+projection (one launch, z=proj) --------
// r14's k1 (pk-f32 gaussian) + k2m (f16-split MFMA) fused: the x = g*P+gamma
// tile is produced and consumed tile-for-tile in the same (H, NBL/64, 3) grid,
// so the 100MB Qg/Kg/Vg HBM round-trip and the k2m launch/staging vanish.
// LDS: gbuf (16.6KB) is overlaid by Xhi/Xlo (16KB) after a barrier (all gbuf
// reads complete first); W tiles (16KB) stage at kernel start under the long
// gaussian phase. Total 32.6KB -> 4 blocks/CU.
__global__ __launch_bounds__(256) void k12(
    const float* __restrict__ P, const float* __restrict__ t,
    const float* __restrict__ mu0, const float* __restrict__ al0, const float* __restrict__ w0, const float* __restrict__ gm0,
    const float* __restrict__ mu1, const float* __restrict__ al1, const float* __restrict__ w1, const float* __restrict__ gm1,
    const float* __restrict__ mu2, const float* __restrict__ al2, const float* __restrict__ w2, const float* __restrict__ gm2,
    const _Float16* __restrict__ Wsp_hi, const _Float16* __restrict__ Wsp_lo,
    _Float16* __restrict__ Qhi, _Float16* __restrict__ Qlo,
    _Float16* __restrict__ Khi, _Float16* __restrict__ Klo,
    unsigned short* __restrict__ Vt)
{
  __shared__ __align__(16) char XU[64 * 65 * 4];        // gbuf f32 ∪ (Xhi|Xlo f16)
  __shared__ __align__(16) _Float16 WhiL[64 * 64];
  __shared__ __align__(16) _Float16 WloL[64 * 64];
  float* gbuf = (float*)XU;
  char* Xhi = XU;                  // 8KB
  char* Xlo = XU + 8192;           // 8KB
  const int h = blockIdx.x, tile = blockIdx.y, p = blockIdx.z;
  const int tid = threadIdx.x, lane = tid & 63;
  const int wv = __builtin_amdgcn_readfirstlane(tid >> 6);   // wave-uniform in SGPR
  const int lrow = lane & 15, lgrp = lane >> 4;
  const int bl0 = tile * 64;

  const float* mu = (p == 0) ? mu0 : (p == 1) ? mu1 : mu2;
  const float* al = (p == 0) ? al0 : (p == 1) ? al1 : al2;
  const float* wp = (p == 0) ? w0  : (p == 1) ? w1  : w2;
  const float* gm = (p == 0) ? gm0 : (p == 1) ? gm1 : gm2;

  // stage W[p][h] early — loads land under the gaussian phase
  {
    const _Float16* wh = Wsp_hi + ((size_t)p * Hc + h) * 4096;
    const _Float16* wl = Wsp_lo + ((size_t)p * Hc + h) * 4096;
    #pragma unroll
    for (int i = tid; i < 512; i += 256){
      const int f = i >> 3, u = i & 7;
      *(f16x8*)((char*)WhiL + f * 128 + swz(f, u) * 16) = *(const f16x8*)(wh + f * 64 + u * 8);
      *(f16x8*)((char*)WloL + f * 128 + swz(f, u) * 16) = *(const f16x8*)(wl + f * 64 + u * 8);
    }
  }

  float tv[8];
  {
    const float4 t0 = *(const float4*)&t[(size_t)(bl0 + lane) * 8];
    const float4 t1 = *(const float4*)&t[(size_t)(bl0 + lane) * 8 + 4];
    tv[0] = t0.x; tv[1] = t0.y; tv[2] = t0.z; tv[3] = t0.w;
    tv[4] = t1.x; tv[5] = t1.y; tv[6] = t1.z; tv[7] = t1.w;
  }

  #pragma unroll 2
  for (int dd = 0; dd < 16; ++dd){
    const int d = wv * 16 + dd;
    const int base = (h * 64 + d) * 64;   // 64 (td,k) terms, wave-uniform -> s_load
    f32x2 g01 = {0.f, 0.f}, g23 = {0.f, 0.f};
    #pragma unroll
    for (int td = 0; td < 8; ++td){
      const float tval = tv[td];
      const f32x2 tt2 = {tval, tval};
      #pragma unroll
      for (int kk = 0; kk < 4; ++kk){
        const int idx = base + td * 8 + kk * 2;
        const f32x2 m2 = *(const f32x2*)&mu[idx];
        const f32x2 a2 = *(const f32x2*)&al[idx];
        const f32x2 w2 = *(const f32x2*)&wp[idx];
        const f32x2 u  = (tt2 - m2) * a2;
        const f32x2 nu = u * u;
        f32x2 e;
        e[0] = __builtin_amdgcn_exp2f(-nu[0]);
        e[1] = __builtin_amdgcn_exp2f(-nu[1]);
        if (kk & 1) g23 += w2 * e;
        else        g01 += w2 * e;
      }
    }
    gbuf[d * 65 + lane] = (g01[0] + g01[1]) + (g23[0] + g23[1]);
  }
  __syncthreads();

  // transposed phase: lanes = d; read g + P (coalesced), x in regs
  float xr[16];
  {
    const int dl = tid & 63, rq = tid >> 6;
    const float gam = gm[h * 64 + dl];
    #pragma unroll 4
    for (int rr = 0; rr < 16; ++rr){
      const int r = rq * 16 + rr;
      const float g  = gbuf[dl * 65 + r];
      const float ph = P[(size_t)(bl0 + r) * DMc + h * 64 + dl];
      xr[rr] = fmaf(g, ph, gam);
    }
  }
  __syncthreads();   // ALL gbuf reads done -> safe to overlay with Xhi/Xlo

  {
    const int dl = tid & 63, rq = tid >> 6;
    const int ub = swz(0, dl >> 3); // placeholder; per-row swz below
    (void)ub;
    #pragma unroll 4
    for (int rr = 0; rr < 16; ++rr){
      const int r = rq * 16 + rr;
      const float a = xr[rr];
      const _Float16 hi = (_Float16)a;
      const _Float16 lo = (_Float16)(a - (float)hi);
      const int off = r * 128 + swz(r, dl >> 3) * 16 + (dl & 7) * 2;
      *(_Float16*)(Xhi + off) = hi;
      *(_Float16*)(Xlo + off) = lo;
    }
  }
  __syncthreads();   // X + W tiles ready

  f32x4 acc[4] = {};
  if (p < 2){
    // D[m][f]: A = X rows (wave owns m in [wv*16, wv*16+16)), B = W
    #pragma unroll
    for (int ks = 0; ks < 2; ++ks){
      const int arow = wv * 16 + lrow;
      const int aoff = arow * 128 + swz(arow, ks * 4 + lgrp) * 16;
      f16x8 xh = *(const f16x8*)(Xhi + aoff);
      f16x8 xl = *(const f16x8*)(Xlo + aoff);
      #pragma unroll
      for (int tf = 0; tf < 4; ++tf){
        const int brow = tf * 16 + lrow;
        const int boff = brow * 128 + swz(brow, ks * 4 + lgrp) * 16;
        f16x8 wh_ = *(const f16x8*)((const char*)WhiL + boff);
        f16x8 wl_ = *(const f16x8*)((const char*)WloL + boff);
        acc[tf] = __builtin_amdgcn_mfma_f32_16x16x32_f16(xh, wh_, acc[tf], 0, 0, 0);
        acc[tf] = __builtin_amdgcn_mfma_f32_16x16x32_f16(xl, wh_, acc[tf], 0, 0, 0);
        acc[tf] = __builtin_amdgcn_mfma_f32_16x16x32_f16(xh, wl_, acc[tf], 0, 0, 0);
      }
    }
  } else {
    // D[f][m] (V^T direct): A = W rows (wave owns f), B = X
    #pragma unroll
    for (int ks = 0; ks < 2; ++ks){
      const int arow = wv * 16 + lrow;
      const int aoff = arow * 128 + swz(arow, ks * 4 + lgrp) * 16;
      f16x8 wh_ = *(const f16x8*)((const char*)WhiL + aoff);
      f16x8 wl_ = *(const f16x8*)((const char*)WloL + aoff);
      #pragma unroll
      for (int mt = 0; mt < 4; ++mt){
        const int brow = mt * 16 + lrow;
        const int boff = brow * 128 + swz(brow, ks * 4 + lgrp) * 16;
        f16x8 xh = *(const f16x8*)(Xhi + boff);
        f16x8 xl = *(const f16x8*)(Xlo + boff);
        acc[mt] = __builtin_amdgcn_mfma_f32_16x16x32_f16(wh_, xh, acc[mt], 0, 0, 0);
        acc[mt] = __builtin_amdgcn_mfma_f32_16x16x32_f16(wl_, xh, acc[mt], 0, 0, 0);
        acc[mt] = __builtin_amdgcn_mfma_f32_16x16x32_f16(wh_, xl, acc[mt], 0, 0, 0);
      }
    }
  }

  const int b = bl0 >> 10, l0 = bl0 & 1023;
  if (p == 0){
    #pragma unroll
    for (int tf = 0; tf < 4; ++tf){
      const int f = tf * 16 + lrow;
      #pragma unroll
      for (int r = 0; r < 4; ++r){
        const int l = l0 + wv * 16 + lgrp * 4 + r;
        const float a = acc[tf][r];
        const _Float16 hi = (_Float16)a;
        const _Float16 lo = (_Float16)(a - (float)hi);
        const size_t o = (((size_t)b * Hc + h) * Lc + l) * 64 + f;
        Qhi[o] = hi; Qlo[o] = lo;
      }
    }
  } else if (p == 1){
    #pragma unroll
    for (int tf = 0; tf < 4; ++tf){
      const int f = tf * 16 + lrow;
      #pragma unroll
      for (int r = 0; r < 4; ++r){
        const int l = l0 + wv * 16 + lgrp * 4 + r;
        const float a = acc[tf][r];
        const _Float16 hi = (_Float16)a;
        const _Float16 lo = (_Float16)(a - (float)hi);
        const size_t o = (((size_t)b * Hc + h) * Lc + l) * 64 + (swz(l, f >> 3) << 3) + (f & 7);
        Khi[o] = hi; Klo[o] = lo;
      }
    }
  } else {
    const size_t basev = (((size_t)b * Hc + h) * 64) * Lc + l0;
    #pragma unroll
    for (int mt = 0; mt < 4; ++mt){
      const int ml = mt * 16 + lrow;
      #pragma unroll
      for (int r = 0; r < 4; ++r){
        const int f = wv * 16 + lgrp * 4 + r;
        Vt[basev + (size_t)f * Lc + (swz(f, ml >> 3) << 3) + (ml & 7)] = f2bf(acc[mt][r]);
      }
    }
  }
}

// ---------------- K3: flash attention, SWAPPED-operand QK^T ------------------
// (r14 form: lane-local softmax, cvt_pk P-write/epilogue, PV swapped)
__global__ __launch_bounds__(256) void k3_attn(
    const _Float16* __restrict__ Qhi, const _Float16* __restrict__ Qlo,
    const _Float16* __restrict__ Khi, const _Float16* __restrict__ Klo,
    const unsigned short* __restrict__ Vt,
    unsigned short* __restrict__ AO)
{
  __shared__ __align__(16) _Float16 KhiL[64 * 64];
  __shared__ __align__(16) _Float16 KloL[64 * 64];
  __shared__ __align__(16) unsigned short VL[64 * 64];   // [f][m]
  __shared__ __align__(16) unsigned short PL[4][16 * 64];
  const int bh = blockIdx.x, qt = blockIdx.y;
  const int tid = threadIdx.x, wv = tid >> 6, lane = tid & 63;
  const int lrow = lane & 15, lgrp = lane >> 4;
  const size_t bhL = (size_t)bh * Lc;

  f16x8 qh[2], ql[2];
  {
    const int qrow = qt * 64 + wv * 16 + lrow;
    const _Float16* q1 = &Qhi[(bhL + qrow) * 64 + lgrp * 8];
    const _Float16* q2 = &Qlo[(bhL + qrow) * 64 + lgrp * 8];
    qh[0] = *(const f16x8*)q1; qh[1] = *(const f16x8*)(q1 + 32);
    ql[0] = *(const f16x8*)q2; ql[1] = *(const f16x8*)(q2 + 32);
  }

  f32x4 o[4] = {};
  float mrun = -1e30f, lrun = 0.f;       // lane-local: row q = lane&15

  const int i0 = tid, i1 = tid + 256;
  const char* kbase = (const char*)(Khi + bhL * 64);
  const char* lbase = (const char*)(Klo + bhL * 64);
  const char* vbase = (const char*)(Vt + (size_t)bh * 64 * Lc);
  const int voff0 = (i0 >> 3) * 2048 + (i0 & 7) * 16;
  const int voff1 = (i1 >> 3) * 2048 + (i1 & 7) * 16;

  // prologue: issue tile 0 loads into staging regs
  f16x8 ra0 = *(const f16x8*)(kbase + i0 * 16);
  f16x8 ra1 = *(const f16x8*)(kbase + i1 * 16);
  f16x8 rb0 = *(const f16x8*)(lbase + i0 * 16);
  f16x8 rb1 = *(const f16x8*)(lbase + i1 * 16);
  s16x8 rc0 = *(const s16x8*)(vbase + voff0);
  s16x8 rc1 = *(const s16x8*)(vbase + voff1);

  #pragma unroll 1
  for (int kt = 0; kt < 16; ++kt){
    __syncthreads();                       // prev tile's LDS consumers done
    *(f16x8*)((char*)KhiL + i0 * 16) = ra0;
    *(f16x8*)((char*)KhiL + i1 * 16) = ra1;
    *(f16x8*)((char*)KloL + i0 * 16) = rb0;
    *(f16x8*)((char*)KloL + i1 * 16) = rb1;
    *(s16x8*)((char*)VL + i0 * 16) = rc0;
    *(s16x8*)((char*)VL + i1 * 16) = rc1;
    if (kt + 1 < 16){                      // issue NEXT tile now; lands under compute
      const char* kn = kbase + (kt + 1) * 8192;
      const char* ln = lbase + (kt + 1) * 8192;
      const char* vn = vbase + (kt + 1) * 128;
      ra0 = *(const f16x8*)(kn + i0 * 16);
      ra1 = *(const f16x8*)(kn + i1 * 16);
      rb0 = *(const f16x8*)(ln + i0 * 16);
      rb1 = *(const f16x8*)(ln + i1 * 16);
      rc0 = *(const s16x8*)(vn + voff0);
      rc1 = *(const s16x8*)(vn + voff1);
    }
    __syncthreads();                       // this tile's LDS ready

    // S^T = K.Q^T (swapped): lane holds S[q=lane&15][m = tt*16 + lgrp*4 + r]
    f32x4 s[4] = {};
    #pragma unroll
    for (int tt = 0; tt < 4; ++tt){
      #pragma unroll
      for (int ks = 0; ks < 2; ++ks){
        const int m = tt * 16 + lrow;
        const int off = m * 128 + swz(m, ks * 4 + lgrp) * 16;
        f16x8 kh_ = *(const f16x8*)((const char*)KhiL + off);
        f16x8 kl_ = *(const f16x8*)((const char*)KloL + off);
        s[tt] = __builtin_amdgcn_mfma_f32_16x16x32_f16(kh_, qh[ks], s[tt], 0, 0, 0);
        s[tt] = __builtin_amdgcn_mfma_f32_16x16x32_f16(kh_, ql[ks], s[tt], 0, 0, 0);
        s[tt] = __builtin_amdgcn_mfma_f32_16x16x32_f16(kl_, qh[ks], s[tt], 0, 0, 0);
      }
    }

    // online softmax: 16 in-reg values + 2 shfls (cross-lgrp)
    float v;
    {
      float v0 = fmaxf(fmaxf(s[0][0], s[0][1]), fmaxf(s[0][2], s[0][3]));
      float v1 = fmaxf(fmaxf(s[1][0], s[1][1]), fmaxf(s[1][2], s[1][3]));
      float v2 = fmaxf(fmaxf(s[2][0], s[2][1]), fmaxf(s[2][2], s[2][3]));
      float v3 = fmaxf(fmaxf(s[3][0], s[3][1]), fmaxf(s[3][2], s[3][3]));
      v = fmaxf(fmaxf(v0, v1), fmaxf(v2, v3));
      v = fmaxf(v, __shfl_xor(v, 16));
      v = fmaxf(v, __shfl_xor(v, 32));
    }
    const float mn = fmaxf(mrun, v);
    const float sc = __builtin_amdgcn_exp2f(mrun - mn);   // arg <= 0
    mrun = mn;

    float rs = 0.f;
    float pp[4][4];
    #pragma unroll
    for (int tt = 0; tt < 4; ++tt){
      #pragma unroll
      for (int r = 0; r < 4; ++r){
        const float p = __builtin_amdgcn_exp2f(s[tt][r] - mn);  // arg <= 0
        rs += p;
        pp[tt][r] = p;
      }
    }
    rs += __shfl_xor(rs, 16);
    rs += __shfl_xor(rs, 32);
    lrun = lrun * sc + rs;
    #pragma unroll
    for (int t2 = 0; t2 < 4; ++t2){
      o[t2][0] *= sc; o[t2][1] *= sc; o[t2][2] *= sc; o[t2][3] *= sc;
    }

    // P -> per-wave LDS: 4x ds_write_b64 (4 contiguous m per (tt)), cvt_pk packed
    short* pw = (short*)PL[wv];
    #pragma unroll
    for (int tt = 0; tt < 4; ++tt){
      uint2 pk;
      pk.x = cvtpk_bf16(pp[tt][0], pp[tt][1]);
      pk.y = cvtpk_bf16(pp[tt][2], pp[tt][3]);
      const int off = lrow * 128 + swz(lrow, tt * 2 + (lgrp >> 1)) * 16 + (lgrp & 1) * 8;
      *(uint2*)((char*)pw + off) = pk;
    }
    // HARD ORDER: mixed-width same-address LDS pair (rule #18 class hazard;
    // fixed r5's post-timing divergence).
    asm volatile("s_waitcnt lgkmcnt(0)" ::: "memory");
    __builtin_amdgcn_sched_barrier(0);

    // PV swapped: o = mfma(V, P) -> O^T[f][q]: cols = q = lane&15 (sc lane-local)
    #pragma unroll
    for (int ks = 0; ks < 2; ++ks){
      const int poff = lrow * 128 + swz(lrow, ks * 4 + lgrp) * 16;
      s16x8 pa = *(const s16x8*)((const char*)pw + poff);
      #pragma unroll
      for (int t2 = 0; t2 < 4; ++t2){
        const int f = t2 * 16 + lrow;
        const int voff = f * 128 + swz(f, ks * 4 + lgrp) * 16;
        s16x8 vb = *(const s16x8*)((const char*)VL + voff);
        o[t2] = __builtin_amdgcn_mfma_f32_16x16x32_bf16(vb, pa, o[t2], 0, 0, 0);
      }
    }
  }

  // epilogue: lane owns row l = qt*64 + wv*16 + (lane&15); f = t2*16 + lgrp*4 + r
  const int b = bh >> 4, hh = bh & 15;
  const float inv = 1.0f / lrun;
  const int l = qt * 64 + wv * 16 + lrow;
  unsigned short* aorow = &AO[((size_t)(b * Lc + l)) * DMc + hh * 64];
  #pragma unroll
  for (int t2 = 0; t2 < 4; ++t2){
    uint2 ov;
    ov.x = cvtpk_bf16(o[t2][0] * inv, o[t2][1] * inv);
    ov.y = cvtpk_bf16(o[t2][2] * inv, o[t2][3] * inv);
    *(uint2*)(aorow + t2 * 16 + lgrp * 4) = ov;
  }
}

// ---------------- K4: out = attn @ W_O^T + b  (bf16 MFMA GEMM, f32 out) ------
// grid (NBL/128, DM/128), block 256 (2x2 waves, each 64x64).
__global__ __launch_bounds__(256) void k4_out(
    const unsigned short* __restrict__ A, const unsigned short* __restrict__ Bw,
    const float* __restrict__ bias, float* __restrict__ out)
{
  __shared__ __align__(16) unsigned short Asl[128 * 64];
  __shared__ __align__(16) unsigned short Bsl[128 * 64];
  const int mt = blockIdx.x, nt = blockIdx.y;
  const int tid = threadIdx.x, wv = tid >> 6, lane = tid & 63;
  const int wr = wv >> 1, wc = wv & 1, lrow = lane & 15, lgrp = lane >> 4;
  f32x4 acc[4][4] = {};
  const char* abase = (const char*)A  + (size_t)mt * 128 * 2048;
  const char* bbase = (const char*)Bw + (size_t)nt * 128 * 2048;

  for (int kt = 0; kt < 16; ++kt){
    __syncthreads();
    #pragma unroll
    for (int q = 0; q < 4; ++q){
      const int i = q * 256 + tid, row = i >> 3, u = i & 7;
      s16x8 av = *(const s16x8*)(abase + (size_t)row * 2048 + kt * 128 + u * 16);
      s16x8 bv = *(const s16x8*)(bbase + (size_t)row * 2048 + kt * 128 + u * 16);
      *(s16x8*)((char*)Asl + row * 128 + swz(row, u) * 16) = av;
      *(s16x8*)((char*)Bsl + row * 128 + swz(row, u) * 16) = bv;
    }
    __syncthreads();
    #pragma unroll
    for (int ks = 0; ks < 2; ++ks){
      s16x8 af[4], bf[4];
      #pragma unroll
      for (int i4 = 0; i4 < 4; ++i4){
        const int row = wr * 64 + i4 * 16 + lrow;
        af[i4] = *(const s16x8*)((const char*)Asl + row * 128 + swz(row, ks * 4 + lgrp) * 16);
        const int col = wc * 64 + i4 * 16 + lrow;
        bf[i4] = *(const s16x8*)((const char*)Bsl + col * 128 + swz(col, ks * 4 + lgrp) * 16);
      }
      #pragma unroll
      for (int i4 = 0; i4 < 4; ++i4)
        #pragma unroll
        for (int j4 = 0; j4 < 4; ++j4)
          acc[i4][j4] = __builtin_amdgcn_mfma_f32_16x16x32_bf16(af[i4], bf[j4], acc[i4][j4], 0, 0, 0);
    }
  }
  #pragma unroll
  for (int i4 = 0; i4 < 4; ++i4)
    #pragma unroll
    for (int j4 = 0; j4 < 4; ++j4){
      const int col = nt * 128 + wc * 64 + j4 * 16 + lrow;
      const float bb = bias[col];
      #pragma unroll
      for (int r = 0; r < 4; ++r){
        const int row = mt * 128 + wr * 64 + i4 * 16 + lgrp * 4 + r;
        out[(size_t)row * DMc + col] = acc[i4][j4][r] + bb;
      }
    }
}

// ---------------- launch -----------------------------------------------------
extern "C" void kernel_launch(void* const* d_in, const int* in_sizes, int n_in,
                              void* d_out, int out_size, void* d_ws, size_t ws_size,
                              hipStream_t stream)
{
  const float* P   = (const float*)d_in[0];
  const float* t   = (const float*)d_in[1];
  const float* muQ = (const float*)d_in[2];
  const float* sgQ = (const float*)d_in[3];
  const float* wQ  = (const float*)d_in[4];
  const float* gQ  = (const float*)d_in[5];
  const float* WQ  = (const float*)d_in[6];
  const float* muK = (const float*)d_in[7];
  const float* sgK = (const float*)d_in[8];
  const float* wK  = (const float*)d_in[9];
  const float* gK  = (const float*)d_in[10];
  const float* WK  = (const float*)d_in[11];
  const float* muV = (const float*)d_in[12];
  const float* sgV = (const float*)d_in[13];
  const float* wV  = (const float*)d_in[14];
  const float* gV  = (const float*)d_in[15];
  const float* WV  = (const float*)d_in[16];
  const float* WO  = (const float*)d_in[17];
  const float* WOb = (const float*)d_in[18];

  char* w = (char*)d_ws;
  auto take = [&](size_t bytes) -> char* {
    char* p = w; w += (bytes + 255) & ~(size_t)255; return p;
  };
  float* aQ = (float*)take((size_t)PAR * 4);
  float* aK = (float*)take((size_t)PAR * 4);
  float* aV = (float*)take((size_t)PAR * 4);
  _Float16* Qhi = (_Float16*)take((size_t)NBL * DMc * 2);
  _Float16* Qlo = (_Float16*)take((size_t)NBL * DMc * 2);
  _Float16* Khi = (_Float16*)take((size_t)NBL * DMc * 2);
  _Float16* Klo = (_Float16*)take((size_t)NBL * DMc * 2);
  unsigned short* Vt    = (unsigned short*)take((size_t)NBL * DMc * 2);
  unsigned short* AO    = (unsigned short*)take((size_t)NBL * DMc * 2);
  unsigned short* WOb16 = (unsigned short*)take((size_t)DMc * DMc * 2);
  _Float16* Wsp_hi = (_Float16*)take((size_t)3 * Hc * 64 * 64 * 2);
  _Float16* Wsp_lo = (_Float16*)take((size_t)3 * Hc * 64 * 64 * 2);
  if ((size_t)(w - (char*)d_ws) > ws_size) return;  // insufficient scratch: bail

  k0_alpha<<<PAR / 256, 256, 0, stream>>>(sgQ, sgK, sgV, aQ, aK, aV);
  k0_wo<<<DMc * DMc / 256, 256, 0, stream>>>(WO, WOb16);
  k0_wsplit<<<(3 * Hc * 64 * 64) / 256, 256, 0, stream>>>(WQ, WK, WV, Wsp_hi, Wsp_lo);
  k12<<<dim3(Hc, NBL / 64, 3), 256, 0, stream>>>(P, t,
      muQ, aQ, wQ, gQ,  muK, aK, wK, gK,  muV, aV, wV, gV,
      Wsp_hi, Wsp_lo, Qhi, Qlo, Khi, Klo, Vt);
  k3_attn<<<dim3(Bc * Hc, Lc / 64), 256, 0, stream>>>(Qhi, Qlo, Khi, Klo, Vt, AO);
  k4_out<<<dim3(NBL / 128, DMc / 128), 256, 0, stream>>>(AO, WOb16, WOb, (float*)d_out);
}

// Round 16
// 205.047 us; speedup vs baseline: 1.0465x; 1.0465x over previous
//
#include <hip/hip_runtime.h>
#include <cstdint>

#define DEVI __device__ __forceinline__

constexpr int Bc = 4, Lc = 1024, DMc = 1024, Hc = 16, TDc = 8, Kc = 8, Dc = 64;
constexpr int NBL = Bc * Lc;               // 4096
constexpr int PAR = Hc * Dc * TDc * Kc;    // 65536 per param array

using f16x8 = __attribute__((ext_vector_type(8))) _Float16;
using f16x4 = __attribute__((ext_vector_type(4))) _Float16;
using s16x8 = __attribute__((ext_vector_type(8))) short;
using s16x4 = __attribute__((ext_vector_type(4))) short;
using f32x4 = __attribute__((ext_vector_type(4))) float;
using f32x2 = __attribute__((ext_vector_type(2))) float;

DEVI unsigned short f2bf(float x){
  union { float f; unsigned u; } v; v.f = x;
  return (unsigned short)((v.u + 0x7fffu + ((v.u >> 16) & 1u)) >> 16);
}

// packed f32x2 -> 2x bf16 in one v_cvt_pk_bf16_f32 (dst.lo = src0, RNE) [T12/m240]
DEVI unsigned cvtpk_bf16(float lo, float hi){
  unsigned r;
  asm("v_cvt_pk_bf16_f32 %0, %1, %2" : "=v"(r) : "v"(lo), "v"(hi));
  return r;
}

// LDS swizzle — ON (write/read pairs audited r0; k2m pre-swizzles K/V global layout).
#define SWZ_ON 1
DEVI int swz(int row, int unit){
#if SWZ_ON
  return unit ^ (row & 7);
#else
  (void)row; return unit;
#endif
}

// ---------------- K0: precompute alpha = sqrt(log2e/2)/sigma ; WO -> bf16 ----
__global__ __launch_bounds__(256) void k0_alpha(
    const float* __restrict__ sQ, const float* __restrict__ sK, const float* __restrict__ sV,
    float* __restrict__ aQ, float* __restrict__ aK, float* __restrict__ aV)
{
  int i = blockIdx.x * 256 + threadIdx.x;
  if (i < PAR){
    const float c = 0.8493218002880191f; // sqrt(log2(e)/2)
    aQ[i] = c / sQ[i];
    aK[i] = c / sK[i];
    aV[i] = c / sV[i];
  }
}

__global__ __launch_bounds__(256) void k0_wo(const float* __restrict__ WO, unsigned short* __restrict__ WOb)
{
  int i = blockIdx.x * 256 + threadIdx.x;
  if (i < DMc * DMc) WOb[i] = f2bf(WO[i]);
}

// W split: [p][h][f][d] transposed f16 hi/lo; W_Q pre-scaled (scale is linear).
__global__ __launch_bounds__(256) void k0_wsplit(
    const float* __restrict__ WQ, const float* __restrict__ WK, const float* __restrict__ WV,
    _Float16* __restrict__ Whi, _Float16* __restrict__ Wlo)
{
  int i = blockIdx.x * 256 + threadIdx.x;
  if (i >= 3 * Hc * 64 * 64) return;
  const int d = i & 63, f = (i >> 6) & 63, h = (i >> 12) & 15, p = i >> 16;
  const float* W = (p == 0) ? WQ : (p == 1) ? WK : WV;
  float v = W[((size_t)h * 64 + d) * 64 + f];
  if (p == 0) v *= 0.18033688011112042f;   // log2(e)/sqrt(D)
  const _Float16 hi = (_Float16)v;
  Whi[i] = hi;
  Wlo[i] = (_Float16)(v - (float)hi);
}

// ---------------- K1: gaussian basis * P + gamma  (f32 out) ------------------
// r14 form (pk-f32 pairs, measured 127us) with d-loop unroll 2->4 for deeper
// s_load overlap (VALUBusy 71% -> residual stall is scalar-load latency).
__global__ __launch_bounds__(256) void k1_gauss(
    const float* __restrict__ P, const float* __restrict__ t,
    const float* __restrict__ mu0, const float* __restrict__ al0, const float* __restrict__ w0, const float* __restrict__ gm0,
    const float* __restrict__ mu1, const float* __restrict__ al1, const float* __restrict__ w1, const float* __restrict__ gm1,
    const float* __restrict__ mu2, const float* __restrict__ al2, const float* __restrict__ w2, const float* __restrict__ gm2,
    float* __restrict__ o0, float* __restrict__ o1, float* __restrict__ o2)
{
  __shared__ float gbuf[64 * 65];
  const int h = blockIdx.x, tile = blockIdx.y, p = blockIdx.z;
  const int tid = threadIdx.x, lane = tid & 63;
  const int wv = __builtin_amdgcn_readfirstlane(tid >> 6);   // wave-uniform in SGPR
  const int bl0 = tile * 64;

  const float* mu = (p == 0) ? mu0 : (p == 1) ? mu1 : mu2;
  const float* al = (p == 0) ? al0 : (p == 1) ? al1 : al2;
  const float* wp = (p == 0) ? w0  : (p == 1) ? w1  : w2;
  const float* gm = (p == 0) ? gm0 : (p == 1) ? gm1 : gm2;
  float*       op = (p == 0) ? o0  : (p == 1) ? o1  : o2;

  float tv[8];
  {
    const float4 t0 = *(const float4*)&t[(size_t)(bl0 + lane) * 8];
    const float4 t1 = *(const float4*)&t[(size_t)(bl0 + lane) * 8 + 4];
    tv[0] = t0.x; tv[1] = t0.y; tv[2] = t0.z; tv[3] = t0.w;
    tv[4] = t1.x; tv[5] = t1.y; tv[6] = t1.z; tv[7] = t1.w;
  }

  #pragma unroll 4
  for (int dd = 0; dd < 16; ++dd){
    const int d = wv * 16 + dd;
    const int base = (h * 64 + d) * 64;   // 64 (td,k) terms, wave-uniform -> s_load
    f32x2 g01 = {0.f, 0.f}, g23 = {0.f, 0.f};
    #pragma unroll
    for (int td = 0; td < 8; ++td){
      const float tval = tv[td];
      const f32x2 tt2 = {tval, tval};
      #pragma unroll
      for (int kk = 0; kk < 4; ++kk){
        const int idx = base + td * 8 + kk * 2;
        const f32x2 m2 = *(const f32x2*)&mu[idx];
        const f32x2 a2 = *(const f32x2*)&al[idx];
        const f32x2 w2 = *(const f32x2*)&wp[idx];
        const f32x2 u  = (tt2 - m2) * a2;     // pk_sub + pk_mul
        const f32x2 nu = u * u;               // pk_mul
        f32x2 e;
        e[0] = __builtin_amdgcn_exp2f(-nu[0]);  // neg folds into src modifier
        e[1] = __builtin_amdgcn_exp2f(-nu[1]);
        if (kk & 1) g23 += w2 * e;            // pk_fma
        else        g01 += w2 * e;
      }
    }
    gbuf[d * 65 + lane] = (g01[0] + g01[1]) + (g23[0] + g23[1]);
  }
  __syncthreads();

  { // transposed write phase: lanes = d (coalesced P read + output write)
    const int dl = tid & 63, rq = tid >> 6;
    const float gam = gm[h * 64 + dl];
    #pragma unroll 4
    for (int rr = 0; rr < 16; ++rr){
      const int r = rq * 16 + rr;
      const float g  = gbuf[dl * 65 + r];
      const float ph = P[(size_t)(bl0 + r) * DMc + h * 64 + dl];
      op[(size_t)(bl0 + r) * DMc + h * 64 + dl] = fmaf(g, ph, gam);
    }
  }
}

// ---------------- K2m: projections via f16-split MFMA (one launch, z=proj) ---
__global__ __launch_bounds__(256) void k2m(
    const float* __restrict__ Qg, const float* __restrict__ Kg, const float* __restrict__ Vg,
    const _Float16* __restrict__ Wsp_hi, const _Float16* __restrict__ Wsp_lo,
    _Float16* __restrict__ Qhi, _Float16* __restrict__ Qlo,
    _Float16* __restrict__ Khi, _Float16* __restrict__ Klo,
    unsigned short* __restrict__ Vt)
{
  __shared__ __align__(16) _Float16 XhiL[64 * 64];
  __shared__ __align__(16) _Float16 XloL[64 * 64];
  __shared__ __align__(16) _Float16 WhiL[64 * 64];
  __shared__ __align__(16) _Float16 WloL[64 * 64];
  const int h = blockIdx.x, tile = blockIdx.y, p = blockIdx.z;
  const int tid = threadIdx.x, lane = tid & 63, wv = tid >> 6;
  const int lrow = lane & 15, lgrp = lane >> 4;
  const int bl0 = tile * 64;

  const float* Xg = (p == 0) ? Qg : (p == 1) ? Kg : Vg;

  // stage X tile (f32 -> hi/lo f16), rows 128B, swizzled 16B units
  for (int i = tid; i < 1024; i += 256){
    const int row = i >> 4, c4 = i & 15;
    const float4 x = *(const float4*)&Xg[(size_t)(bl0 + row) * DMc + h * 64 + c4 * 4];
    const float xs[4] = {x.x, x.y, x.z, x.w};
    f16x4 hx, lx;
    #pragma unroll
    for (int j = 0; j < 4; ++j){
      hx[j] = (_Float16)xs[j];
      lx[j] = (_Float16)(xs[j] - (float)hx[j]);
    }
    const int off = row * 128 + swz(row, c4 >> 1) * 16 + (c4 & 1) * 8;
    *(f16x4*)((char*)XhiL + off) = hx;
    *(f16x4*)((char*)XloL + off) = lx;
  }
  // stage W[p][h] (f16, already transposed [f][d] + pre-scaled for Q)
  {
    const _Float16* wh = Wsp_hi + ((size_t)p * Hc + h) * 4096;
    const _Float16* wl = Wsp_lo + ((size_t)p * Hc + h) * 4096;
    for (int i = tid; i < 512; i += 256){
      const int f = i >> 3, u = i & 7;
      *(f16x8*)((char*)WhiL + f * 128 + swz(f, u) * 16) = *(const f16x8*)(wh + f * 64 + u * 8);
      *(f16x8*)((char*)WloL + f * 128 + swz(f, u) * 16) = *(const f16x8*)(wl + f * 64 + u * 8);
    }
  }
  __syncthreads();

  f32x4 acc[4] = {};
  if (p < 2){
    // D[m][f]: A = X rows (wave owns m in [wv*16, wv*16+16)), B = W
    #pragma unroll
    for (int ks = 0; ks < 2; ++ks){
      const int arow = wv * 16 + lrow;
      const int aoff = arow * 128 + swz(arow, ks * 4 + lgrp) * 16;
      f16x8 xh = *(const f16x8*)((const char*)XhiL + aoff);
      f16x8 xl = *(const f16x8*)((const char*)XloL + aoff);
      #pragma unroll
      for (int tf = 0; tf < 4; ++tf){
        const int brow = tf * 16 + lrow;
        const int boff = brow * 128 + swz(brow, ks * 4 + lgrp) * 16;
        f16x8 wh_ = *(const f16x8*)((const char*)WhiL + boff);
        f16x8 wl_ = *(const f16x8*)((const char*)WloL + boff);
        acc[tf] = __builtin_amdgcn_mfma_f32_16x16x32_f16(xh, wh_, acc[tf], 0, 0, 0);
        acc[tf] = __builtin_amdgcn_mfma_f32_16x16x32_f16(xl, wh_, acc[tf], 0, 0, 0);
        acc[tf] = __builtin_amdgcn_mfma_f32_16x16x32_f16(xh, wl_, acc[tf], 0, 0, 0);
      }
    }
  } else {
    // D[f][m] (V^T direct): A = W rows (wave owns f), B = X
    #pragma unroll
    for (int ks = 0; ks < 2; ++ks){
      const int arow = wv * 16 + lrow;
      const int aoff = arow * 128 + swz(arow, ks * 4 + lgrp) * 16;
      f16x8 wh_ = *(const f16x8*)((const char*)WhiL + aoff);
      f16x8 wl_ = *(const f16x8*)((const char*)WloL + aoff);
      #pragma unroll
      for (int mt = 0; mt < 4; ++mt){
        const int brow = mt * 16 + lrow;
        const int boff = brow * 128 + swz(brow, ks * 4 + lgrp) * 16;
        f16x8 xh = *(const f16x8*)((const char*)XhiL + boff);
        f16x8 xl = *(const f16x8*)((const char*)XloL + boff);
        acc[mt] = __builtin_amdgcn_mfma_f32_16x16x32_f16(wh_, xh, acc[mt], 0, 0, 0);
        acc[mt] = __builtin_amdgcn_mfma_f32_16x16x32_f16(wl_, xh, acc[mt], 0, 0, 0);
        acc[mt] = __builtin_amdgcn_mfma_f32_16x16x32_f16(wh_, xl, acc[mt], 0, 0, 0);
      }
    }
  }

  const int b = bl0 >> 10, l0 = bl0 & 1023;
  if (p == 0){
    #pragma unroll
    for (int tf = 0; tf < 4; ++tf){
      const int f = tf * 16 + lrow;
      #pragma unroll
      for (int r = 0; r < 4; ++r){
        const int l = l0 + wv * 16 + lgrp * 4 + r;
        const float a = acc[tf][r];
        const _Float16 hi = (_Float16)a;
        const _Float16 lo = (_Float16)(a - (float)hi);
        const size_t o = (((size_t)b * Hc + h) * Lc + l) * 64 + f;
        Qhi[o] = hi; Qlo[o] = lo;
      }
    }
  } else if (p == 1){
    #pragma unroll
    for (int tf = 0; tf < 4; ++tf){
      const int f = tf * 16 + lrow;
      #pragma unroll
      for (int r = 0; r < 4; ++r){
        const int l = l0 + wv * 16 + lgrp * 4 + r;
        const float a = acc[tf][r];
        const _Float16 hi = (_Float16)a;
        const _Float16 lo = (_Float16)(a - (float)hi);
        const size_t o = (((size_t)b * Hc + h) * Lc + l) * 64 + (swz(l, f >> 3) << 3) + (f & 7);
        Khi[o] = hi; Klo[o] = lo;
      }
    }
  } else {
    const size_t basev = (((size_t)b * Hc + h) * 64) * Lc + l0;
    #pragma unroll
    for (int mt = 0; mt < 4; ++mt){
      const int ml = mt * 16 + lrow;
      #pragma unroll
      for (int r = 0; r < 4; ++r){
        const int f = wv * 16 + lgrp * 4 + r;
        Vt[basev + (size_t)f * Lc + (swz(f, ml >> 3) << 3) + (ml & 7)] = f2bf(acc[mt][r]);
      }
    }
  }
}

// ---------------- K3: flash attention, SWAPPED-operand QK^T ------------------
// (r14 form: lane-local softmax, cvt_pk P-write/epilogue, PV swapped)
__global__ __launch_bounds__(256) void k3_attn(
    const _Float16* __restrict__ Qhi, const _Float16* __restrict__ Qlo,
    const _Float16* __restrict__ Khi, const _Float16* __restrict__ Klo,
    const unsigned short* __restrict__ Vt,
    unsigned short* __restrict__ AO)
{
  __shared__ __align__(16) _Float16 KhiL[64 * 64];
  __shared__ __align__(16) _Float16 KloL[64 * 64];
  __shared__ __align__(16) unsigned short VL[64 * 64];   // [f][m]
  __shared__ __align__(16) unsigned short PL[4][16 * 64];
  const int bh = blockIdx.x, qt = blockIdx.y;
  const int tid = threadIdx.x, wv = tid >> 6, lane = tid & 63;
  const int lrow = lane & 15, lgrp = lane >> 4;
  const size_t bhL = (size_t)bh * Lc;

  f16x8 qh[2], ql[2];
  {
    const int qrow = qt * 64 + wv * 16 + lrow;
    const _Float16* q1 = &Qhi[(bhL + qrow) * 64 + lgrp * 8];
    const _Float16* q2 = &Qlo[(bhL + qrow) * 64 + lgrp * 8];
    qh[0] = *(const f16x8*)q1; qh[1] = *(const f16x8*)(q1 + 32);
    ql[0] = *(const f16x8*)q2; ql[1] = *(const f16x8*)(q2 + 32);
  }

  f32x4 o[4] = {};
  float mrun = -1e30f, lrun = 0.f;       // lane-local: row q = lane&15

  const int i0 = tid, i1 = tid + 256;
  const char* kbase = (const char*)(Khi + bhL * 64);
  const char* lbase = (const char*)(Klo + bhL * 64);
  const char* vbase = (const char*)(Vt + (size_t)bh * 64 * Lc);
  const int voff0 = (i0 >> 3) * 2048 + (i0 & 7) * 16;
  const int voff1 = (i1 >> 3) * 2048 + (i1 & 7) * 16;

  // prologue: issue tile 0 loads into staging regs
  f16x8 ra0 = *(const f16x8*)(kbase + i0 * 16);
  f16x8 ra1 = *(const f16x8*)(kbase + i1 * 16);
  f16x8 rb0 = *(const f16x8*)(lbase + i0 * 16);
  f16x8 rb1 = *(const f16x8*)(lbase + i1 * 16);
  s16x8 rc0 = *(const s16x8*)(vbase + voff0);
  s16x8 rc1 = *(const s16x8*)(vbase + voff1);

  #pragma unroll 1
  for (int kt = 0; kt < 16; ++kt){
    __syncthreads();                       // prev tile's LDS consumers done
    *(f16x8*)((char*)KhiL + i0 * 16) = ra0;
    *(f16x8*)((char*)KhiL + i1 * 16) = ra1;
    *(f16x8*)((char*)KloL + i0 * 16) = rb0;
    *(f16x8*)((char*)KloL + i1 * 16) = rb1;
    *(s16x8*)((char*)VL + i0 * 16) = rc0;
    *(s16x8*)((char*)VL + i1 * 16) = rc1;
    if (kt + 1 < 16){                      // issue NEXT tile now; lands under compute
      const char* kn = kbase + (kt + 1) * 8192;
      const char* ln = lbase + (kt + 1) * 8192;
      const char* vn = vbase + (kt + 1) * 128;
      ra0 = *(const f16x8*)(kn + i0 * 16);
      ra1 = *(const f16x8*)(kn + i1 * 16);
      rb0 = *(const f16x8*)(ln + i0 * 16);
      rb1 = *(const f16x8*)(ln + i1 * 16);
      rc0 = *(const s16x8*)(vn + voff0);
      rc1 = *(const s16x8*)(vn + voff1);
    }
    __syncthreads();                       // this tile's LDS ready

    // S^T = K.Q^T (swapped): lane holds S[q=lane&15][m = tt*16 + lgrp*4 + r]
    f32x4 s[4] = {};
    #pragma unroll
    for (int tt = 0; tt < 4; ++tt){
      #pragma unroll
      for (int ks = 0; ks < 2; ++ks){
        const int m = tt * 16 + lrow;
        const int off = m * 128 + swz(m, ks * 4 + lgrp) * 16;
        f16x8 kh_ = *(const f16x8*)((const char*)KhiL + off);
        f16x8 kl_ = *(const f16x8*)((const char*)KloL + off);
        s[tt] = __builtin_amdgcn_mfma_f32_16x16x32_f16(kh_, qh[ks], s[tt], 0, 0, 0);
        s[tt] = __builtin_amdgcn_mfma_f32_16x16x32_f16(kh_, ql[ks], s[tt], 0, 0, 0);
        s[tt] = __builtin_amdgcn_mfma_f32_16x16x32_f16(kl_, qh[ks], s[tt], 0, 0, 0);
      }
    }

    // online softmax: 16 in-reg values + 2 shfls (cross-lgrp)
    float v;
    {
      float v0 = fmaxf(fmaxf(s[0][0], s[0][1]), fmaxf(s[0][2], s[0][3]));
      float v1 = fmaxf(fmaxf(s[1][0], s[1][1]), fmaxf(s[1][2], s[1][3]));
      float v2 = fmaxf(fmaxf(s[2][0], s[2][1]), fmaxf(s[2][2], s[2][3]));
      float v3 = fmaxf(fmaxf(s[3][0], s[3][1]), fmaxf(s[3][2], s[3][3]));
      v = fmaxf(fmaxf(v0, v1), fmaxf(v2, v3));
      v = fmaxf(v, __shfl_xor(v, 16));
      v = fmaxf(v, __shfl_xor(v, 32));
    }
    const float mn = fmaxf(mrun, v);
    const float sc = __builtin_amdgcn_exp2f(mrun - mn);   // arg <= 0
    mrun = mn;

    float rs = 0.f;
    float pp[4][4];
    #pragma unroll
    for (int tt = 0; tt < 4; ++tt){
      #pragma unroll
      for (int r = 0; r < 4; ++r){
        const float p = __builtin_amdgcn_exp2f(s[tt][r] - mn);  // arg <= 0
        rs += p;
        pp[tt][r] = p;
      }
    }
    rs += __shfl_xor(rs, 16);
    rs += __shfl_xor(rs, 32);
    lrun = lrun * sc + rs;
    #pragma unroll
    for (int t2 = 0; t2 < 4; ++t2){
      o[t2][0] *= sc; o[t2][1] *= sc; o[t2][2] *= sc; o[t2][3] *= sc;
    }

    // P -> per-wave LDS: 4x ds_write_b64 (4 contiguous m per (tt)), cvt_pk packed
    short* pw = (short*)PL[wv];
    #pragma unroll
    for (int tt = 0; tt < 4; ++tt){
      uint2 pk;
      pk.x = cvtpk_bf16(pp[tt][0], pp[tt][1]);
      pk.y = cvtpk_bf16(pp[tt][2], pp[tt][3]);
      const int off = lrow * 128 + swz(lrow, tt * 2 + (lgrp >> 1)) * 16 + (lgrp & 1) * 8;
      *(uint2*)((char*)pw + off) = pk;
    }
    // HARD ORDER: mixed-width same-address LDS pair (rule #18 class hazard;
    // fixed r5's post-timing divergence).
    asm volatile("s_waitcnt lgkmcnt(0)" ::: "memory");
    __builtin_amdgcn_sched_barrier(0);

    // PV swapped: o = mfma(V, P) -> O^T[f][q]: cols = q = lane&15 (sc lane-local)
    #pragma unroll
    for (int ks = 0; ks < 2; ++ks){
      const int poff = lrow * 128 + swz(lrow, ks * 4 + lgrp) * 16;
      s16x8 pa = *(const s16x8*)((const char*)pw + poff);
      #pragma unroll
      for (int t2 = 0; t2 < 4; ++t2){
        const int f = t2 * 16 + lrow;
        const int voff = f * 128 + swz(f, ks * 4 + lgrp) * 16;
        s16x8 vb = *(const s16x8*)((const char*)VL + voff);
        o[t2] = __builtin_amdgcn_mfma_f32_16x16x32_bf16(vb, pa, o[t2], 0, 0, 0);
      }
    }
  }

  // epilogue: lane owns row l = qt*64 + wv*16 + (lane&15); f = t2*16 + lgrp*4 + r
  const int b = bh >> 4, hh = bh & 15;
  const float inv = 1.0f / lrun;
  const int l = qt * 64 + wv * 16 + lrow;
  unsigned short* aorow = &AO[((size_t)(b * Lc + l)) * DMc + hh * 64];
  #pragma unroll
  for (int t2 = 0; t2 < 4; ++t2){
    uint2 ov;
    ov.x = cvtpk_bf16(o[t2][0] * inv, o[t2][1] * inv);
    ov.y = cvtpk_bf16(o[t2][2] * inv, o[t2][3] * inv);
    *(uint2*)(aorow + t2 * 16 + lgrp * 4) = ov;
  }
}

// ---------------- K4: out = attn @ W_O^T + b  (bf16 MFMA GEMM, f32 out) ------
// grid (NBL/128, DM/128), block 256 (2x2 waves, each 64x64).
__global__ __launch_bounds__(256) void k4_out(
    const unsigned short* __restrict__ A, const unsigned short* __restrict__ Bw,
    const float* __restrict__ bias, float* __restrict__ out)
{
  __shared__ __align__(16) unsigned short Asl[128 * 64];
  __shared__ __align__(16) unsigned short Bsl[128 * 64];
  const int mt = blockIdx.x, nt = blockIdx.y;
  const int tid = threadIdx.x, wv = tid >> 6, lane = tid & 63;
  const int wr = wv >> 1, wc = wv & 1, lrow = lane & 15, lgrp = lane >> 4;
  f32x4 acc[4][4] = {};
  const char* abase = (const char*)A  + (size_t)mt * 128 * 2048;
  const char* bbase = (const char*)Bw + (size_t)nt * 128 * 2048;

  for (int kt = 0; kt < 16; ++kt){
    __syncthreads();
    #pragma unroll
    for (int q = 0; q < 4; ++q){
      const int i = q * 256 + tid, row = i >> 3, u = i & 7;
      s16x8 av = *(const s16x8*)(abase + (size_t)row * 2048 + kt * 128 + u * 16);
      s16x8 bv = *(const s16x8*)(bbase + (size_t)row * 2048 + kt * 128 + u * 16);
      *(s16x8*)((char*)Asl + row * 128 + swz(row, u) * 16) = av;
      *(s16x8*)((char*)Bsl + row * 128 + swz(row, u) * 16) = bv;
    }
    __syncthreads();
    #pragma unroll
    for (int ks = 0; ks < 2; ++ks){
      s16x8 af[4], bf[4];
      #pragma unroll
      for (int i4 = 0; i4 < 4; ++i4){
        const int row = wr * 64 + i4 * 16 + lrow;
        af[i4] = *(const s16x8*)((const char*)Asl + row * 128 + swz(row, ks * 4 + lgrp) * 16);
        const int col = wc * 64 + i4 * 16 + lrow;
        bf[i4] = *(const s16x8*)((const char*)Bsl + col * 128 + swz(col, ks * 4 + lgrp) * 16);
      }
      #pragma unroll
      for (int i4 = 0; i4 < 4; ++i4)
        #pragma unroll
        for (int j4 = 0; j4 < 4; ++j4)
          acc[i4][j4] = __builtin_amdgcn_mfma_f32_16x16x32_bf16(af[i4], bf[j4], acc[i4][j4], 0, 0, 0);
    }
  }
  #pragma unroll
  for (int i4 = 0; i4 < 4; ++i4)
    #pragma unroll
    for (int j4 = 0; j4 < 4; ++j4){
      const int col = nt * 128 + wc * 64 + j4 * 16 + lrow;
      const float bb = bias[col];
      #pragma unroll
      for (int r = 0; r < 4; ++r){
        const int row = mt * 128 + wr * 64 + i4 * 16 + lgrp * 4 + r;
        out[(size_t)row * DMc + col] = acc[i4][j4][r] + bb;
      }
    }
}

// ---------------- launch -----------------------------------------------------
extern "C" void kernel_launch(void* const* d_in, const int* in_sizes, int n_in,
                              void* d_out, int out_size, void* d_ws, size_t ws_size,
                              hipStream_t stream)
{
  const float* P   = (const float*)d_in[0];
  const float* t   = (const float*)d_in[1];
  const float* muQ = (const float*)d_in[2];
  const float* sgQ = (const float*)d_in[3];
  const float* wQ  = (const float*)d_in[4];
  const float* gQ  = (const float*)d_in[5];
  const float* WQ  = (const float*)d_in[6];
  const float* muK = (const float*)d_in[7];
  const float* sgK = (const float*)d_in[8];
  const float* wK  = (const float*)d_in[9];
  const float* gK  = (const float*)d_in[10];
  const float* WK  = (const float*)d_in[11];
  const float* muV = (const float*)d_in[12];
  const float* sgV = (const float*)d_in[13];
  const float* wV  = (const float*)d_in[14];
  const float* gV  = (const float*)d_in[15];
  const float* WV  = (const float*)d_in[16];
  const float* WO  = (const float*)d_in[17];
  const float* WOb = (const float*)d_in[18];

  char* w = (char*)d_ws;
  auto take = [&](size_t bytes) -> char* {
    char* p = w; w += (bytes + 255) & ~(size_t)255; return p;
  };
  float* aQ = (float*)take((size_t)PAR * 4);
  float* aK = (float*)take((size_t)PAR * 4);
  float* aV = (float*)take((size_t)PAR * 4);
  float* Qg = (float*)take((size_t)NBL * DMc * 4);
  float* Kg = (float*)take((size_t)NBL * DMc * 4);
  float* Vg = (float*)take((size_t)NBL * DMc * 4);
  _Float16* Qhi = (_Float16*)take((size_t)NBL * DMc * 2);
  _Float16* Qlo = (_Float16*)take((size_t)NBL * DMc * 2);
  _Float16* Khi = (_Float16*)take((size_t)NBL * DMc * 2);
  _Float16* Klo = (_Float16*)take((size_t)NBL * DMc * 2);
  unsigned short* Vt    = (unsigned short*)take((size_t)NBL * DMc * 2);
  unsigned short* AO    = (unsigned short*)take((size_t)NBL * DMc * 2);
  unsigned short* WOb16 = (unsigned short*)take((size_t)DMc * DMc * 2);
  _Float16* Wsp_hi = (_Float16*)take((size_t)3 * Hc * 64 * 64 * 2);
  _Float16* Wsp_lo = (_Float16*)take((size_t)3 * Hc * 64 * 64 * 2);
  if ((size_t)(w - (char*)d_ws) > ws_size) return;  // insufficient scratch: bail

  k0_alpha<<<PAR / 256, 256, 0, stream>>>(sgQ, sgK, sgV, aQ, aK, aV);
  k0_wo<<<DMc * DMc / 256, 256, 0, stream>>>(WO, WOb16);
  k0_wsplit<<<(3 * Hc * 64 * 64) / 256, 256, 0, stream>>>(WQ, WK, WV, Wsp_hi, Wsp_lo);
  k1_gauss<<<dim3(Hc, NBL / 64, 3), 256, 0, stream>>>(P, t,
      muQ, aQ, wQ, gQ,  muK, aK, wK, gK,  muV, aV, wV, gV,  Qg, Kg, Vg);
  k2m<<<dim3(Hc, NBL / 64, 3), 256, 0, stream>>>(Qg, Kg, Vg, Wsp_hi, Wsp_lo,
      Qhi, Qlo, Khi, Klo, Vt);
  k3_attn<<<dim3(Bc * Hc, Lc / 64), 256, 0, stream>>>(Qhi, Qlo, Khi, Klo, Vt, AO);
  k4_out<<<dim3(NBL / 128, DMc / 128), 256, 0, stream>>>(AO, WOb16, WOb, (float*)d_out);
}

// Round 17
// 204.555 us; speedup vs baseline: 1.0490x; 1.0024x over previous
//
#include <hip/hip_runtime.h>
#include <cstdint>

#define DEVI __device__ __forceinline__

constexpr int Bc = 4, Lc = 1024, DMc = 1024, Hc = 16, TDc = 8, Kc = 8, Dc = 64;
constexpr int NBL = Bc * Lc;               // 4096
constexpr int PAR = Hc * Dc * TDc * Kc;    // 65536 per param array

using f16x8 = __attribute__((ext_vector_type(8))) _Float16;
using f16x4 = __attribute__((ext_vector_type(4))) _Float16;
using s16x8 = __attribute__((ext_vector_type(8))) short;
using s16x4 = __attribute__((ext_vector_type(4))) short;
using f32x4 = __attribute__((ext_vector_type(4))) float;
using f32x2 = __attribute__((ext_vector_type(2))) float;

DEVI unsigned short f2bf(float x){
  union { float f; unsigned u; } v; v.f = x;
  return (unsigned short)((v.u + 0x7fffu + ((v.u >> 16) & 1u)) >> 16);
}

// packed f32x2 -> 2x bf16 in one v_cvt_pk_bf16_f32 (dst.lo = src0, RNE) [T12/m240]
DEVI unsigned cvtpk_bf16(float lo, float hi){
  unsigned r;
  asm("v_cvt_pk_bf16_f32 %0, %1, %2" : "=v"(r) : "v"(lo), "v"(hi));
  return r;
}

// LDS swizzle — ON (write/read pairs audited r0; k2m pre-swizzles K/V global layout).
#define SWZ_ON 1
DEVI int swz(int row, int unit){
#if SWZ_ON
  return unit ^ (row & 7);
#else
  (void)row; return unit;
#endif
}

// ---------------- K0a: pack params contiguously (frees k1 arg SGPRs) ---------
// PK[p][{mu,alpha,w}][PAR], GA[p][Hc*64]; alpha = sqrt(log2e/2)/sigma.
__global__ __launch_bounds__(256) void k0_pack(
    const float* __restrict__ muQ, const float* __restrict__ sgQ, const float* __restrict__ wQ, const float* __restrict__ gQ,
    const float* __restrict__ muK, const float* __restrict__ sgK, const float* __restrict__ wK, const float* __restrict__ gK,
    const float* __restrict__ muV, const float* __restrict__ sgV, const float* __restrict__ wV, const float* __restrict__ gV,
    float* __restrict__ PK, float* __restrict__ GA)
{
  const float c = 0.8493218002880191f; // sqrt(log2(e)/2)
  const int i = blockIdx.x * 256 + threadIdx.x;
  if (i < 3 * PAR){
    const int p = i / PAR, j = i - p * PAR;
    const float* mu = (p == 0) ? muQ : (p == 1) ? muK : muV;
    const float* sg = (p == 0) ? sgQ : (p == 1) ? sgK : sgV;
    const float* w  = (p == 0) ? wQ  : (p == 1) ? wK  : wV;
    PK[((size_t)p * 3 + 0) * PAR + j] = mu[j];
    PK[((size_t)p * 3 + 1) * PAR + j] = c / sg[j];
    PK[((size_t)p * 3 + 2) * PAR + j] = w[j];
  }
  if (i < 3 * Hc * 64){
    const int p = i / (Hc * 64), j = i - p * (Hc * 64);
    const float* g = (p == 0) ? gQ : (p == 1) ? gK : gV;
    GA[i] = g[j];
  }
}

__global__ __launch_bounds__(256) void k0_wo(const float* __restrict__ WO, unsigned short* __restrict__ WOb)
{
  int i = blockIdx.x * 256 + threadIdx.x;
  if (i < DMc * DMc) WOb[i] = f2bf(WO[i]);
}

// W split: [p][h][f][d] transposed f16 hi/lo; W_Q pre-scaled (scale is linear).
__global__ __launch_bounds__(256) void k0_wsplit(
    const float* __restrict__ WQ, const float* __restrict__ WK, const float* __restrict__ WV,
    _Float16* __restrict__ Whi, _Float16* __restrict__ Wlo)
{
  int i = blockIdx.x * 256 + threadIdx.x;
  if (i >= 3 * Hc * 64 * 64) return;
  const int d = i & 63, f = (i >> 6) & 63, h = (i >> 12) & 15, p = i >> 16;
  const float* W = (p == 0) ? WQ : (p == 1) ? WK : WV;
  float v = W[((size_t)h * 64 + d) * 64 + f];
  if (p == 0) v *= 0.18033688011112042f;   // log2(e)/sqrt(D)
  const _Float16 hi = (_Float16)v;
  Whi[i] = hi;
  Wlo[i] = (_Float16)(v - (float)hi);
}

// ---------------- K1: gaussian basis * P + gamma  (f32 out) ------------------
// r14 pk-f32 form (127us), 5-pointer signature (was 16): frees ~24 arg SGPRs
// so the compiler can keep more param s_load chunks in flight (the residual
// ~30% stall is SMEM-miss latency bounded by SGPR prefetch budget).
__global__ __launch_bounds__(256) void k1_gauss(
    const float* __restrict__ P, const float* __restrict__ t,
    const float* __restrict__ PK, const float* __restrict__ GA,
    float* __restrict__ OG)
{
  __shared__ float gbuf[64 * 65];
  const int h = blockIdx.x, tile = blockIdx.y, p = blockIdx.z;
  const int tid = threadIdx.x, lane = tid & 63;
  const int wv = __builtin_amdgcn_readfirstlane(tid >> 6);   // wave-uniform in SGPR
  const int bl0 = tile * 64;

  const float* mu = PK + ((size_t)p * 3 + 0) * PAR;
  const float* al = PK + ((size_t)p * 3 + 1) * PAR;
  const float* wp = PK + ((size_t)p * 3 + 2) * PAR;
  const float* gm = GA + p * (Hc * 64);
  float*       op = OG + (size_t)p * NBL * DMc;

  float tv[8];
  {
    const float4 t0 = *(const float4*)&t[(size_t)(bl0 + lane) * 8];
    const float4 t1 = *(const float4*)&t[(size_t)(bl0 + lane) * 8 + 4];
    tv[0] = t0.x; tv[1] = t0.y; tv[2] = t0.z; tv[3] = t0.w;
    tv[4] = t1.x; tv[5] = t1.y; tv[6] = t1.z; tv[7] = t1.w;
  }

  #pragma unroll 2
  for (int dd = 0; dd < 16; ++dd){
    const int d = wv * 16 + dd;
    const int base = (h * 64 + d) * 64;   // 64 (td,k) terms, wave-uniform -> s_load
    f32x2 g01 = {0.f, 0.f}, g23 = {0.f, 0.f};
    #pragma unroll
    for (int td = 0; td < 8; ++td){
      const float tval = tv[td];
      const f32x2 tt2 = {tval, tval};
      #pragma unroll
      for (int kk = 0; kk < 4; ++kk){
        const int idx = base + td * 8 + kk * 2;
        const f32x2 m2 = *(const f32x2*)&mu[idx];
        const f32x2 a2 = *(const f32x2*)&al[idx];
        const f32x2 w2 = *(const f32x2*)&wp[idx];
        const f32x2 u  = (tt2 - m2) * a2;     // pk_sub + pk_mul
        const f32x2 nu = u * u;               // pk_mul
        f32x2 e;
        e[0] = __builtin_amdgcn_exp2f(-nu[0]);  // neg folds into src modifier
        e[1] = __builtin_amdgcn_exp2f(-nu[1]);
        if (kk & 1) g23 += w2 * e;            // pk_fma
        else        g01 += w2 * e;
      }
    }
    gbuf[d * 65 + lane] = (g01[0] + g01[1]) + (g23[0] + g23[1]);
  }
  __syncthreads();

  { // transposed write phase: lanes = d (coalesced P read + output write)
    const int dl = tid & 63, rq = tid >> 6;
    const float gam = gm[h * 64 + dl];
    #pragma unroll 4
    for (int rr = 0; rr < 16; ++rr){
      const int r = rq * 16 + rr;
      const float g  = gbuf[dl * 65 + r];
      const float ph = P[(size_t)(bl0 + r) * DMc + h * 64 + dl];
      op[(size_t)(bl0 + r) * DMc + h * 64 + dl] = fmaf(g, ph, gam);
    }
  }
}

// ---------------- K2m: projections via f16-split MFMA (one launch, z=proj) ---
__global__ __launch_bounds__(256) void k2m(
    const float* __restrict__ Qg, const float* __restrict__ Kg, const float* __restrict__ Vg,
    const _Float16* __restrict__ Wsp_hi, const _Float16* __restrict__ Wsp_lo,
    _Float16* __restrict__ Qhi, _Float16* __restrict__ Qlo,
    _Float16* __restrict__ Khi, _Float16* __restrict__ Klo,
    unsigned short* __restrict__ Vt)
{
  __shared__ __align__(16) _Float16 XhiL[64 * 64];
  __shared__ __align__(16) _Float16 XloL[64 * 64];
  __shared__ __align__(16) _Float16 WhiL[64 * 64];
  __shared__ __align__(16) _Float16 WloL[64 * 64];
  const int h = blockIdx.x, tile = blockIdx.y, p = blockIdx.z;
  const int tid = threadIdx.x, lane = tid & 63, wv = tid >> 6;
  const int lrow = lane & 15, lgrp = lane >> 4;
  const int bl0 = tile * 64;

  const float* Xg = (p == 0) ? Qg : (p == 1) ? Kg : Vg;

  // stage X tile (f32 -> hi/lo f16), rows 128B, swizzled 16B units
  for (int i = tid; i < 1024; i += 256){
    const int row = i >> 4, c4 = i & 15;
    const float4 x = *(const float4*)&Xg[(size_t)(bl0 + row) * DMc + h * 64 + c4 * 4];
    const float xs[4] = {x.x, x.y, x.z, x.w};
    f16x4 hx, lx;
    #pragma unroll
    for (int j = 0; j < 4; ++j){
      hx[j] = (_Float16)xs[j];
      lx[j] = (_Float16)(xs[j] - (float)hx[j]);
    }
    const int off = row * 128 + swz(row, c4 >> 1) * 16 + (c4 & 1) * 8;
    *(f16x4*)((char*)XhiL + off) = hx;
    *(f16x4*)((char*)XloL + off) = lx;
  }
  // stage W[p][h] (f16, already transposed [f][d] + pre-scaled for Q)
  {
    const _Float16* wh = Wsp_hi + ((size_t)p * Hc + h) * 4096;
    const _Float16* wl = Wsp_lo + ((size_t)p * Hc + h) * 4096;
    for (int i = tid; i < 512; i += 256){
      const int f = i >> 3, u = i & 7;
      *(f16x8*)((char*)WhiL + f * 128 + swz(f, u) * 16) = *(const f16x8*)(wh + f * 64 + u * 8);
      *(f16x8*)((char*)WloL + f * 128 + swz(f, u) * 16) = *(const f16x8*)(wl + f * 64 + u * 8);
    }
  }
  __syncthreads();

  f32x4 acc[4] = {};
  if (p < 2){
    // D[m][f]: A = X rows (wave owns m in [wv*16, wv*16+16)), B = W
    #pragma unroll
    for (int ks = 0; ks < 2; ++ks){
      const int arow = wv * 16 + lrow;
      const int aoff = arow * 128 + swz(arow, ks * 4 + lgrp) * 16;
      f16x8 xh = *(const f16x8*)((const char*)XhiL + aoff);
      f16x8 xl = *(const f16x8*)((const char*)XloL + aoff);
      #pragma unroll
      for (int tf = 0; tf < 4; ++tf){
        const int brow = tf * 16 + lrow;
        const int boff = brow * 128 + swz(brow, ks * 4 + lgrp) * 16;
        f16x8 wh_ = *(const f16x8*)((const char*)WhiL + boff);
        f16x8 wl_ = *(const f16x8*)((const char*)WloL + boff);
        acc[tf] = __builtin_amdgcn_mfma_f32_16x16x32_f16(xh, wh_, acc[tf], 0, 0, 0);
        acc[tf] = __builtin_amdgcn_mfma_f32_16x16x32_f16(xl, wh_, acc[tf], 0, 0, 0);
        acc[tf] = __builtin_amdgcn_mfma_f32_16x16x32_f16(xh, wl_, acc[tf], 0, 0, 0);
      }
    }
  } else {
    // D[f][m] (V^T direct): A = W rows (wave owns f), B = X
    #pragma unroll
    for (int ks = 0; ks < 2; ++ks){
      const int arow = wv * 16 + lrow;
      const int aoff = arow * 128 + swz(arow, ks * 4 + lgrp) * 16;
      f16x8 wh_ = *(const f16x8*)((const char*)WhiL + aoff);
      f16x8 wl_ = *(const f16x8*)((const char*)WloL + aoff);
      #pragma unroll
      for (int mt = 0; mt < 4; ++mt){
        const int brow = mt * 16 + lrow;
        const int boff = brow * 128 + swz(brow, ks * 4 + lgrp) * 16;
        f16x8 xh = *(const f16x8*)((const char*)XhiL + boff);
        f16x8 xl = *(const f16x8*)((const char*)XloL + boff);
        acc[mt] = __builtin_amdgcn_mfma_f32_16x16x32_f16(wh_, xh, acc[mt], 0, 0, 0);
        acc[mt] = __builtin_amdgcn_mfma_f32_16x16x32_f16(wl_, xh, acc[mt], 0, 0, 0);
        acc[mt] = __builtin_amdgcn_mfma_f32_16x16x32_f16(wh_, xl, acc[mt], 0, 0, 0);
      }
    }
  }

  const int b = bl0 >> 10, l0 = bl0 & 1023;
  if (p == 0){
    #pragma unroll
    for (int tf = 0; tf < 4; ++tf){
      const int f = tf * 16 + lrow;
      #pragma unroll
      for (int r = 0; r < 4; ++r){
        const int l = l0 + wv * 16 + lgrp * 4 + r;
        const float a = acc[tf][r];
        const _Float16 hi = (_Float16)a;
        const _Float16 lo = (_Float16)(a - (float)hi);
        const size_t o = (((size_t)b * Hc + h) * Lc + l) * 64 + f;
        Qhi[o] = hi; Qlo[o] = lo;
      }
    }
  } else if (p == 1){
    #pragma unroll
    for (int tf = 0; tf < 4; ++tf){
      const int f = tf * 16 + lrow;
      #pragma unroll
      for (int r = 0; r < 4; ++r){
        const int l = l0 + wv * 16 + lgrp * 4 + r;
        const float a = acc[tf][r];
        const _Float16 hi = (_Float16)a;
        const _Float16 lo = (_Float16)(a - (float)hi);
        const size_t o = (((size_t)b * Hc + h) * Lc + l) * 64 + (swz(l, f >> 3) << 3) + (f & 7);
        Khi[o] = hi; Klo[o] = lo;
      }
    }
  } else {
    const size_t basev = (((size_t)b * Hc + h) * 64) * Lc + l0;
    #pragma unroll
    for (int mt = 0; mt < 4; ++mt){
      const int ml = mt * 16 + lrow;
      #pragma unroll
      for (int r = 0; r < 4; ++r){
        const int f = wv * 16 + lgrp * 4 + r;
        Vt[basev + (size_t)f * Lc + (swz(f, ml >> 3) << 3) + (ml & 7)] = f2bf(acc[mt][r]);
      }
    }
  }
}

// ---------------- K3: flash attention, SWAPPED-operand QK^T ------------------
// (r14 form: lane-local softmax, cvt_pk P-write/epilogue, PV swapped)
__global__ __launch_bounds__(256) void k3_attn(
    const _Float16* __restrict__ Qhi, const _Float16* __restrict__ Qlo,
    const _Float16* __restrict__ Khi, const _Float16* __restrict__ Klo,
    const unsigned short* __restrict__ Vt,
    unsigned short* __restrict__ AO)
{
  __shared__ __align__(16) _Float16 KhiL[64 * 64];
  __shared__ __align__(16) _Float16 KloL[64 * 64];
  __shared__ __align__(16) unsigned short VL[64 * 64];   // [f][m]
  __shared__ __align__(16) unsigned short PL[4][16 * 64];
  const int bh = blockIdx.x, qt = blockIdx.y;
  const int tid = threadIdx.x, wv = tid >> 6, lane = tid & 63;
  const int lrow = lane & 15, lgrp = lane >> 4;
  const size_t bhL = (size_t)bh * Lc;

  f16x8 qh[2], ql[2];
  {
    const int qrow = qt * 64 + wv * 16 + lrow;
    const _Float16* q1 = &Qhi[(bhL + qrow) * 64 + lgrp * 8];
    const _Float16* q2 = &Qlo[(bhL + qrow) * 64 + lgrp * 8];
    qh[0] = *(const f16x8*)q1; qh[1] = *(const f16x8*)(q1 + 32);
    ql[0] = *(const f16x8*)q2; ql[1] = *(const f16x8*)(q2 + 32);
  }

  f32x4 o[4] = {};
  float mrun = -1e30f, lrun = 0.f;       // lane-local: row q = lane&15

  const int i0 = tid, i1 = tid + 256;
  const char* kbase = (const char*)(Khi + bhL * 64);
  const char* lbase = (const char*)(Klo + bhL * 64);
  const char* vbase = (const char*)(Vt + (size_t)bh * 64 * Lc);
  const int voff0 = (i0 >> 3) * 2048 + (i0 & 7) * 16;
  const int voff1 = (i1 >> 3) * 2048 + (i1 & 7) * 16;

  // prologue: issue tile 0 loads into staging regs
  f16x8 ra0 = *(const f16x8*)(kbase + i0 * 16);
  f16x8 ra1 = *(const f16x8*)(kbase + i1 * 16);
  f16x8 rb0 = *(const f16x8*)(lbase + i0 * 16);
  f16x8 rb1 = *(const f16x8*)(lbase + i1 * 16);
  s16x8 rc0 = *(const s16x8*)(vbase + voff0);
  s16x8 rc1 = *(const s16x8*)(vbase + voff1);

  #pragma unroll 1
  for (int kt = 0; kt < 16; ++kt){
    __syncthreads();                       // prev tile's LDS consumers done
    *(f16x8*)((char*)KhiL + i0 * 16) = ra0;
    *(f16x8*)((char*)KhiL + i1 * 16) = ra1;
    *(f16x8*)((char*)KloL + i0 * 16) = rb0;
    *(f16x8*)((char*)KloL + i1 * 16) = rb1;
    *(s16x8*)((char*)VL + i0 * 16) = rc0;
    *(s16x8*)((char*)VL + i1 * 16) = rc1;
    if (kt + 1 < 16){                      // issue NEXT tile now; lands under compute
      const char* kn = kbase + (kt + 1) * 8192;
      const char* ln = lbase + (kt + 1) * 8192;
      const char* vn = vbase + (kt + 1) * 128;
      ra0 = *(const f16x8*)(kn + i0 * 16);
      ra1 = *(const f16x8*)(kn + i1 * 16);
      rb0 = *(const f16x8*)(ln + i0 * 16);
      rb1 = *(const f16x8*)(ln + i1 * 16);
      rc0 = *(const s16x8*)(vn + voff0);
      rc1 = *(const s16x8*)(vn + voff1);
    }
    __syncthreads();                       // this tile's LDS ready

    // S^T = K.Q^T (swapped): lane holds S[q=lane&15][m = tt*16 + lgrp*4 + r]
    f32x4 s[4] = {};
    #pragma unroll
    for (int tt = 0; tt < 4; ++tt){
      #pragma unroll
      for (int ks = 0; ks < 2; ++ks){
        const int m = tt * 16 + lrow;
        const int off = m * 128 + swz(m, ks * 4 + lgrp) * 16;
        f16x8 kh_ = *(const f16x8*)((const char*)KhiL + off);
        f16x8 kl_ = *(const f16x8*)((const char*)KloL + off);
        s[tt] = __builtin_amdgcn_mfma_f32_16x16x32_f16(kh_, qh[ks], s[tt], 0, 0, 0);
        s[tt] = __builtin_amdgcn_mfma_f32_16x16x32_f16(kh_, ql[ks], s[tt], 0, 0, 0);
        s[tt] = __builtin_amdgcn_mfma_f32_16x16x32_f16(kl_, qh[ks], s[tt], 0, 0, 0);
      }
    }

    // online softmax: 16 in-reg values + 2 shfls (cross-lgrp)
    float v;
    {
      float v0 = fmaxf(fmaxf(s[0][0], s[0][1]), fmaxf(s[0][2], s[0][3]));
      float v1 = fmaxf(fmaxf(s[1][0], s[1][1]), fmaxf(s[1][2], s[1][3]));
      float v2 = fmaxf(fmaxf(s[2][0], s[2][1]), fmaxf(s[2][2], s[2][3]));
      float v3 = fmaxf(fmaxf(s[3][0], s[3][1]), fmaxf(s[3][2], s[3][3]));
      v = fmaxf(fmaxf(v0, v1), fmaxf(v2, v3));
      v = fmaxf(v, __shfl_xor(v, 16));
      v = fmaxf(v, __shfl_xor(v, 32));
    }
    const float mn = fmaxf(mrun, v);
    const float sc = __builtin_amdgcn_exp2f(mrun - mn);   // arg <= 0
    mrun = mn;

    float rs = 0.f;
    float pp[4][4];
    #pragma unroll
    for (int tt = 0; tt < 4; ++tt){
      #pragma unroll
      for (int r = 0; r < 4; ++r){
        const float p = __builtin_amdgcn_exp2f(s[tt][r] - mn);  // arg <= 0
        rs += p;
        pp[tt][r] = p;
      }
    }
    rs += __shfl_xor(rs, 16);
    rs += __shfl_xor(rs, 32);
    lrun = lrun * sc + rs;
    #pragma unroll
    for (int t2 = 0; t2 < 4; ++t2){
      o[t2][0] *= sc; o[t2][1] *= sc; o[t2][2] *= sc; o[t2][3] *= sc;
    }

    // P -> per-wave LDS: 4x ds_write_b64 (4 contiguous m per (tt)), cvt_pk packed
    short* pw = (short*)PL[wv];
    #pragma unroll
    for (int tt = 0; tt < 4; ++tt){
      uint2 pk;
      pk.x = cvtpk_bf16(pp[tt][0], pp[tt][1]);
      pk.y = cvtpk_bf16(pp[tt][2], pp[tt][3]);
      const int off = lrow * 128 + swz(lrow, tt * 2 + (lgrp >> 1)) * 16 + (lgrp & 1) * 8;
      *(uint2*)((char*)pw + off) = pk;
    }
    // HARD ORDER: mixed-width same-address LDS pair (rule #18 class hazard;
    // fixed r5's post-timing divergence).
    asm volatile("s_waitcnt lgkmcnt(0)" ::: "memory");
    __builtin_amdgcn_sched_barrier(0);

    // PV swapped: o = mfma(V, P) -> O^T[f][q]: cols = q = lane&15 (sc lane-local)
    #pragma unroll
    for (int ks = 0; ks < 2; ++ks){
      const int poff = lrow * 128 + swz(lrow, ks * 4 + lgrp) * 16;
      s16x8 pa = *(const s16x8*)((const char*)pw + poff);
      #pragma unroll
      for (int t2 = 0; t2 < 4; ++t2){
        const int f = t2 * 16 + lrow;
        const int voff = f * 128 + swz(f, ks * 4 + lgrp) * 16;
        s16x8 vb = *(const s16x8*)((const char*)VL + voff);
        o[t2] = __builtin_amdgcn_mfma_f32_16x16x32_bf16(vb, pa, o[t2], 0, 0, 0);
      }
    }
  }

  // epilogue: lane owns row l = qt*64 + wv*16 + (lane&15); f = t2*16 + lgrp*4 + r
  const int b = bh >> 4, hh = bh & 15;
  const float inv = 1.0f / lrun;
  const int l = qt * 64 + wv * 16 + lrow;
  unsigned short* aorow = &AO[((size_t)(b * Lc + l)) * DMc + hh * 64];
  #pragma unroll
  for (int t2 = 0; t2 < 4; ++t2){
    uint2 ov;
    ov.x = cvtpk_bf16(o[t2][0] * inv, o[t2][1] * inv);
    ov.y = cvtpk_bf16(o[t2][2] * inv, o[t2][3] * inv);
    *(uint2*)(aorow + t2 * 16 + lgrp * 4) = ov;
  }
}

// ---------------- K4: out = attn @ W_O^T + b  (bf16 MFMA GEMM, f32 out) ------
// grid (NBL/128, DM/128), block 256 (2x2 waves, each 64x64).
__global__ __launch_bounds__(256) void k4_out(
    const unsigned short* __restrict__ A, const unsigned short* __restrict__ Bw,
    const float* __restrict__ bias, float* __restrict__ out)
{
  __shared__ __align__(16) unsigned short Asl[128 * 64];
  __shared__ __align__(16) unsigned short Bsl[128 * 64];
  const int mt = blockIdx.x, nt = blockIdx.y;
  const int tid = threadIdx.x, wv = tid >> 6, lane = tid & 63;
  const int wr = wv >> 1, wc = wv & 1, lrow = lane & 15, lgrp = lane >> 4;
  f32x4 acc[4][4] = {};
  const char* abase = (const char*)A  + (size_t)mt * 128 * 2048;
  const char* bbase = (const char*)Bw + (size_t)nt * 128 * 2048;

  for (int kt = 0; kt < 16; ++kt){
    __syncthreads();
    #pragma unroll
    for (int q = 0; q < 4; ++q){
      const int i = q * 256 + tid, row = i >> 3, u = i & 7;
      s16x8 av = *(const s16x8*)(abase + (size_t)row * 2048 + kt * 128 + u * 16);
      s16x8 bv = *(const s16x8*)(bbase + (size_t)row * 2048 + kt * 128 + u * 16);
      *(s16x8*)((char*)Asl + row * 128 + swz(row, u) * 16) = av;
      *(s16x8*)((char*)Bsl + row * 128 + swz(row, u) * 16) = bv;
    }
    __syncthreads();
    #pragma unroll
    for (int ks = 0; ks < 2; ++ks){
      s16x8 af[4], bf[4];
      #pragma unroll
      for (int i4 = 0; i4 < 4; ++i4){
        const int row = wr * 64 + i4 * 16 + lrow;
        af[i4] = *(const s16x8*)((const char*)Asl + row * 128 + swz(row, ks * 4 + lgrp) * 16);
        const int col = wc * 64 + i4 * 16 + lrow;
        bf[i4] = *(const s16x8*)((const char*)Bsl + col * 128 + swz(col, ks * 4 + lgrp) * 16);
      }
      #pragma unroll
      for (int i4 = 0; i4 < 4; ++i4)
        #pragma unroll
        for (int j4 = 0; j4 < 4; ++j4)
          acc[i4][j4] = __builtin_amdgcn_mfma_f32_16x16x32_bf16(af[i4], bf[j4], acc[i4][j4], 0, 0, 0);
    }
  }
  #pragma unroll
  for (int i4 = 0; i4 < 4; ++i4)
    #pragma unroll
    for (int j4 = 0; j4 < 4; ++j4){
      const int col = nt * 128 + wc * 64 + j4 * 16 + lrow;
      const float bb = bias[col];
      #pragma unroll
      for (int r = 0; r < 4; ++r){
        const int row = mt * 128 + wr * 64 + i4 * 16 + lgrp * 4 + r;
        out[(size_t)row * DMc + col] = acc[i4][j4][r] + bb;
      }
    }
}

// ---------------- launch -----------------------------------------------------
extern "C" void kernel_launch(void* const* d_in, const int* in_sizes, int n_in,
                              void* d_out, int out_size, void* d_ws, size_t ws_size,
                              hipStream_t stream)
{
  const float* P   = (const float*)d_in[0];
  const float* t   = (const float*)d_in[1];
  const float* muQ = (const float*)d_in[2];
  const float* sgQ = (const float*)d_in[3];
  const float* wQ  = (const float*)d_in[4];
  const float* gQ  = (const float*)d_in[5];
  const float* WQ  = (const float*)d_in[6];
  const float* muK = (const float*)d_in[7];
  const float* sgK = (const float*)d_in[8];
  const float* wK  = (const float*)d_in[9];
  const float* gK  = (const float*)d_in[10];
  const float* WK  = (const float*)d_in[11];
  const float* muV = (const float*)d_in[12];
  const float* sgV = (const float*)d_in[13];
  const float* wV  = (const float*)d_in[14];
  const float* gV  = (const float*)d_in[15];
  const float* WV  = (const float*)d_in[16];
  const float* WO  = (const float*)d_in[17];
  const float* WOb = (const float*)d_in[18];

  char* w = (char*)d_ws;
  auto take = [&](size_t bytes) -> char* {
    char* p = w; w += (bytes + 255) & ~(size_t)255; return p;
  };
  float* PKb = (float*)take((size_t)3 * 3 * PAR * 4);
  float* GAb = (float*)take((size_t)3 * Hc * 64 * 4);
  float* OG  = (float*)take((size_t)3 * NBL * DMc * 4);   // Qg|Kg|Vg contiguous
  _Float16* Qhi = (_Float16*)take((size_t)NBL * DMc * 2);
  _Float16* Qlo = (_Float16*)take((size_t)NBL * DMc * 2);
  _Float16* Khi = (_Float16*)take((size_t)NBL * DMc * 2);
  _Float16* Klo = (_Float16*)take((size_t)NBL * DMc * 2);
  unsigned short* Vt    = (unsigned short*)take((size_t)NBL * DMc * 2);
  unsigned short* AO    = (unsigned short*)take((size_t)NBL * DMc * 2);
  unsigned short* WOb16 = (unsigned short*)take((size_t)DMc * DMc * 2);
  _Float16* Wsp_hi = (_Float16*)take((size_t)3 * Hc * 64 * 64 * 2);
  _Float16* Wsp_lo = (_Float16*)take((size_t)3 * Hc * 64 * 64 * 2);
  if ((size_t)(w - (char*)d_ws) > ws_size) return;  // insufficient scratch: bail

  float* Qg = OG;
  float* Kg = OG + (size_t)NBL * DMc;
  float* Vg = OG + (size_t)2 * NBL * DMc;

  k0_pack<<<(3 * PAR + 255) / 256, 256, 0, stream>>>(
      muQ, sgQ, wQ, gQ, muK, sgK, wK, gK, muV, sgV, wV, gV, PKb, GAb);
  k0_wo<<<DMc * DMc / 256, 256, 0, stream>>>(WO, WOb16);
  k0_wsplit<<<(3 * Hc * 64 * 64) / 256, 256, 0, stream>>>(WQ, WK, WV, Wsp_hi, Wsp_lo);
  k1_gauss<<<dim3(Hc, NBL / 64, 3), 256, 0, stream>>>(P, t, PKb, GAb, OG);
  k2m<<<dim3(Hc, NBL / 64, 3), 256, 0, stream>>>(Qg, Kg, Vg, Wsp_hi, Wsp_lo,
      Qhi, Qlo, Khi, Klo, Vt);
  k3_attn<<<dim3(Bc * Hc, Lc / 64), 256, 0, stream>>>(Qhi, Qlo, Khi, Klo, Vt, AO);
  k4_out<<<dim3(NBL / 128, DMc / 128), 256, 0, stream>>>(AO, WOb16, WOb, (float*)d_out);
}

// Round 18
// 190.823 us; speedup vs baseline: 1.1245x; 1.0720x over previous
//
#include <hip/hip_runtime.h>
#include <cstdint>

#define DEVI __device__ __forceinline__

constexpr int Bc = 4, Lc = 1024, DMc = 1024, Hc = 16, TDc = 8, Kc = 8, Dc = 64;
constexpr int NBL = Bc * Lc;               // 4096
constexpr int PAR = Hc * Dc * TDc * Kc;    // 65536 per param array

using f16x8 = __attribute__((ext_vector_type(8))) _Float16;
using f16x4 = __attribute__((ext_vector_type(4))) _Float16;
using s16x8 = __attribute__((ext_vector_type(8))) short;
using s16x4 = __attribute__((ext_vector_type(4))) short;
using f32x4 = __attribute__((ext_vector_type(4))) float;
using f32x2 = __attribute__((ext_vector_type(2))) float;

DEVI unsigned short f2bf(float x){
  union { float f; unsigned u; } v; v.f = x;
  return (unsigned short)((v.u + 0x7fffu + ((v.u >> 16) & 1u)) >> 16);
}

// packed f32x2 -> 2x bf16 in one v_cvt_pk_bf16_f32 (dst.lo = src0, RNE) [T12/m240]
DEVI unsigned cvtpk_bf16(float lo, float hi){
  unsigned r;
  asm("v_cvt_pk_bf16_f32 %0, %1, %2" : "=v"(r) : "v"(lo), "v"(hi));
  return r;
}

// LDS swizzle — ON (write/read pairs audited r0; k2m pre-swizzles K/V global layout).
#define SWZ_ON 1
DEVI int swz(int row, int unit){
#if SWZ_ON
  return unit ^ (row & 7);
#else
  (void)row; return unit;
#endif
}

// ---------------- K0: all prep in ONE dispatch (pack params / WO->bf16 / W split)
__global__ __launch_bounds__(256) void k0_all(
    const float* __restrict__ muQ, const float* __restrict__ sgQ, const float* __restrict__ wQ, const float* __restrict__ gQ,
    const float* __restrict__ muK, const float* __restrict__ sgK, const float* __restrict__ wK, const float* __restrict__ gK,
    const float* __restrict__ muV, const float* __restrict__ sgV, const float* __restrict__ wV, const float* __restrict__ gV,
    const float* __restrict__ WQ, const float* __restrict__ WK, const float* __restrict__ WV,
    const float* __restrict__ WO,
    float* __restrict__ PK, float* __restrict__ GA,
    _Float16* __restrict__ Whi, _Float16* __restrict__ Wlo,
    unsigned short* __restrict__ WOb)
{
  const int bx = blockIdx.x;
  if (bx < 4096){                                  // WO -> bf16 (1M elems)
    const int i = bx * 256 + threadIdx.x;
    WOb[i] = f2bf(WO[i]);
  } else if (bx < 4096 + 768){                     // param pack (3*PAR)
    const float c = 0.8493218002880191f;           // sqrt(log2(e)/2)
    const int i = (bx - 4096) * 256 + threadIdx.x;
    const int p = i / PAR, j = i - p * PAR;
    const float* mu = (p == 0) ? muQ : (p == 1) ? muK : muV;
    const float* sg = (p == 0) ? sgQ : (p == 1) ? sgK : sgV;
    const float* w  = (p == 0) ? wQ  : (p == 1) ? wK  : wV;
    PK[((size_t)p * 3 + 0) * PAR + j] = mu[j];
    PK[((size_t)p * 3 + 1) * PAR + j] = c / sg[j];
    PK[((size_t)p * 3 + 2) * PAR + j] = w[j];
    if (i < 3 * Hc * 64){
      const int pp = i / (Hc * 64), jj = i - pp * (Hc * 64);
      const float* g = (pp == 0) ? gQ : (pp == 1) ? gK : gV;
      GA[i] = g[jj];
    }
  } else {                                         // W split (3*H*64*64)
    const int i = (bx - 4096 - 768) * 256 + threadIdx.x;
    const int d = i & 63, f = (i >> 6) & 63, h = (i >> 12) & 15, p = i >> 16;
    const float* W = (p == 0) ? WQ : (p == 1) ? WK : WV;
    float v = W[((size_t)h * 64 + d) * 64 + f];
    if (p == 0) v *= 0.18033688011112042f;         // log2(e)/sqrt(D)
    const _Float16 hi = (_Float16)v;
    Whi[i] = hi;
    Wlo[i] = (_Float16)(v - (float)hi);
  }
}

// ---------------- K1: gaussian basis * P + gamma  (f32 out) ------------------
// r17 form (119.5us): pk-f32 pairs, 5-pointer signature.
__global__ __launch_bounds__(256) void k1_gauss(
    const float* __restrict__ P, const float* __restrict__ t,
    const float* __restrict__ PK, const float* __restrict__ GA,
    float* __restrict__ OG)
{
  __shared__ float gbuf[64 * 65];
  const int h = blockIdx.x, tile = blockIdx.y, p = blockIdx.z;
  const int tid = threadIdx.x, lane = tid & 63;
  const int wv = __builtin_amdgcn_readfirstlane(tid >> 6);   // wave-uniform in SGPR
  const int bl0 = tile * 64;

  const float* mu = PK + ((size_t)p * 3 + 0) * PAR;
  const float* al = PK + ((size_t)p * 3 + 1) * PAR;
  const float* wp = PK + ((size_t)p * 3 + 2) * PAR;
  const float* gm = GA + p * (Hc * 64);
  float*       op = OG + (size_t)p * NBL * DMc;

  float tv[8];
  {
    const float4 t0 = *(const float4*)&t[(size_t)(bl0 + lane) * 8];
    const float4 t1 = *(const float4*)&t[(size_t)(bl0 + lane) * 8 + 4];
    tv[0] = t0.x; tv[1] = t0.y; tv[2] = t0.z; tv[3] = t0.w;
    tv[4] = t1.x; tv[5] = t1.y; tv[6] = t1.z; tv[7] = t1.w;
  }

  #pragma unroll 2
  for (int dd = 0; dd < 16; ++dd){
    const int d = wv * 16 + dd;
    const int base = (h * 64 + d) * 64;   // 64 (td,k) terms, wave-uniform -> s_load
    f32x2 g01 = {0.f, 0.f}, g23 = {0.f, 0.f};
    #pragma unroll
    for (int td = 0; td < 8; ++td){
      const float tval = tv[td];
      const f32x2 tt2 = {tval, tval};
      #pragma unroll
      for (int kk = 0; kk < 4; ++kk){
        const int idx = base + td * 8 + kk * 2;
        const f32x2 m2 = *(const f32x2*)&mu[idx];
        const f32x2 a2 = *(const f32x2*)&al[idx];
        const f32x2 w2 = *(const f32x2*)&wp[idx];
        const f32x2 u  = (tt2 - m2) * a2;     // pk_sub + pk_mul
        const f32x2 nu = u * u;               // pk_mul
        f32x2 e;
        e[0] = __builtin_amdgcn_exp2f(-nu[0]);  // neg folds into src modifier
        e[1] = __builtin_amdgcn_exp2f(-nu[1]);
        if (kk & 1) g23 += w2 * e;            // pk_fma
        else        g01 += w2 * e;
      }
    }
    gbuf[d * 65 + lane] = (g01[0] + g01[1]) + (g23[0] + g23[1]);
  }
  __syncthreads();

  { // transposed write phase: lanes = d (coalesced P read + output write)
    const int dl = tid & 63, rq = tid >> 6;
    const float gam = gm[h * 64 + dl];
    #pragma unroll 4
    for (int rr = 0; rr < 16; ++rr){
      const int r = rq * 16 + rr;
      const float g  = gbuf[dl * 65 + r];
      const float ph = P[(size_t)(bl0 + r) * DMc + h * 64 + dl];
      op[(size_t)(bl0 + r) * DMc + h * 64 + dl] = fmaf(g, ph, gam);
    }
  }
}

// ---------------- K2m: projections via f16-split MFMA (one launch, z=proj) ---
__global__ __launch_bounds__(256) void k2m(
    const float* __restrict__ Qg, const float* __restrict__ Kg, const float* __restrict__ Vg,
    const _Float16* __restrict__ Wsp_hi, const _Float16* __restrict__ Wsp_lo,
    _Float16* __restrict__ Qhi, _Float16* __restrict__ Qlo,
    _Float16* __restrict__ Khi, _Float16* __restrict__ Klo,
    unsigned short* __restrict__ Vt)
{
  __shared__ __align__(16) _Float16 XhiL[64 * 64];
  __shared__ __align__(16) _Float16 XloL[64 * 64];
  __shared__ __align__(16) _Float16 WhiL[64 * 64];
  __shared__ __align__(16) _Float16 WloL[64 * 64];
  const int h = blockIdx.x, tile = blockIdx.y, p = blockIdx.z;
  const int tid = threadIdx.x, lane = tid & 63, wv = tid >> 6;
  const int lrow = lane & 15, lgrp = lane >> 4;
  const int bl0 = tile * 64;

  const float* Xg = (p == 0) ? Qg : (p == 1) ? Kg : Vg;

  // stage X tile (f32 -> hi/lo f16), rows 128B, swizzled 16B units
  for (int i = tid; i < 1024; i += 256){
    const int row = i >> 4, c4 = i & 15;
    const float4 x = *(const float4*)&Xg[(size_t)(bl0 + row) * DMc + h * 64 + c4 * 4];
    const float xs[4] = {x.x, x.y, x.z, x.w};
    f16x4 hx, lx;
    #pragma unroll
    for (int j = 0; j < 4; ++j){
      hx[j] = (_Float16)xs[j];
      lx[j] = (_Float16)(xs[j] - (float)hx[j]);
    }
    const int off = row * 128 + swz(row, c4 >> 1) * 16 + (c4 & 1) * 8;
    *(f16x4*)((char*)XhiL + off) = hx;
    *(f16x4*)((char*)XloL + off) = lx;
  }
  // stage W[p][h] (f16, already transposed [f][d] + pre-scaled for Q)
  {
    const _Float16* wh = Wsp_hi + ((size_t)p * Hc + h) * 4096;
    const _Float16* wl = Wsp_lo + ((size_t)p * Hc + h) * 4096;
    for (int i = tid; i < 512; i += 256){
      const int f = i >> 3, u = i & 7;
      *(f16x8*)((char*)WhiL + f * 128 + swz(f, u) * 16) = *(const f16x8*)(wh + f * 64 + u * 8);
      *(f16x8*)((char*)WloL + f * 128 + swz(f, u) * 16) = *(const f16x8*)(wl + f * 64 + u * 8);
    }
  }
  __syncthreads();

  f32x4 acc[4] = {};
  if (p < 2){
    // D[m][f]: A = X rows (wave owns m in [wv*16, wv*16+16)), B = W
    #pragma unroll
    for (int ks = 0; ks < 2; ++ks){
      const int arow = wv * 16 + lrow;
      const int aoff = arow * 128 + swz(arow, ks * 4 + lgrp) * 16;
      f16x8 xh = *(const f16x8*)((const char*)XhiL + aoff);
      f16x8 xl = *(const f16x8*)((const char*)XloL + aoff);
      #pragma unroll
      for (int tf = 0; tf < 4; ++tf){
        const int brow = tf * 16 + lrow;
        const int boff = brow * 128 + swz(brow, ks * 4 + lgrp) * 16;
        f16x8 wh_ = *(const f16x8*)((const char*)WhiL + boff);
        f16x8 wl_ = *(const f16x8*)((const char*)WloL + boff);
        acc[tf] = __builtin_amdgcn_mfma_f32_16x16x32_f16(xh, wh_, acc[tf], 0, 0, 0);
        acc[tf] = __builtin_amdgcn_mfma_f32_16x16x32_f16(xl, wh_, acc[tf], 0, 0, 0);
        acc[tf] = __builtin_amdgcn_mfma_f32_16x16x32_f16(xh, wl_, acc[tf], 0, 0, 0);
      }
    }
  } else {
    // D[f][m] (V^T direct): A = W rows (wave owns f), B = X
    #pragma unroll
    for (int ks = 0; ks < 2; ++ks){
      const int arow = wv * 16 + lrow;
      const int aoff = arow * 128 + swz(arow, ks * 4 + lgrp) * 16;
      f16x8 wh_ = *(const f16x8*)((const char*)WhiL + aoff);
      f16x8 wl_ = *(const f16x8*)((const char*)WloL + aoff);
      #pragma unroll
      for (int mt = 0; mt < 4; ++mt){
        const int brow = mt * 16 + lrow;
        const int boff = brow * 128 + swz(brow, ks * 4 + lgrp) * 16;
        f16x8 xh = *(const f16x8*)((const char*)XhiL + boff);
        f16x8 xl = *(const f16x8*)((const char*)XloL + boff);
        acc[mt] = __builtin_amdgcn_mfma_f32_16x16x32_f16(wh_, xh, acc[mt], 0, 0, 0);
        acc[mt] = __builtin_amdgcn_mfma_f32_16x16x32_f16(wl_, xh, acc[mt], 0, 0, 0);
        acc[mt] = __builtin_amdgcn_mfma_f32_16x16x32_f16(wh_, xl, acc[mt], 0, 0, 0);
      }
    }
  }

  const int b = bl0 >> 10, l0 = bl0 & 1023;
  if (p == 0){
    #pragma unroll
    for (int tf = 0; tf < 4; ++tf){
      const int f = tf * 16 + lrow;
      #pragma unroll
      for (int r = 0; r < 4; ++r){
        const int l = l0 + wv * 16 + lgrp * 4 + r;
        const float a = acc[tf][r];
        const _Float16 hi = (_Float16)a;
        const _Float16 lo = (_Float16)(a - (float)hi);
        const size_t o = (((size_t)b * Hc + h) * Lc + l) * 64 + f;
        Qhi[o] = hi; Qlo[o] = lo;
      }
    }
  } else if (p == 1){
    #pragma unroll
    for (int tf = 0; tf < 4; ++tf){
      const int f = tf * 16 + lrow;
      #pragma unroll
      for (int r = 0; r < 4; ++r){
        const int l = l0 + wv * 16 + lgrp * 4 + r;
        const float a = acc[tf][r];
        const _Float16 hi = (_Float16)a;
        const _Float16 lo = (_Float16)(a - (float)hi);
        const size_t o = (((size_t)b * Hc + h) * Lc + l) * 64 + (swz(l, f >> 3) << 3) + (f & 7);
        Khi[o] = hi; Klo[o] = lo;
      }
    }
  } else {
    const size_t basev = (((size_t)b * Hc + h) * 64) * Lc + l0;
    #pragma unroll
    for (int mt = 0; mt < 4; ++mt){
      const int ml = mt * 16 + lrow;
      #pragma unroll
      for (int r = 0; r < 4; ++r){
        const int f = wv * 16 + lgrp * 4 + r;
        Vt[basev + (size_t)f * Lc + (swz(f, ml >> 3) << 3) + (ml & 7)] = f2bf(acc[mt][r]);
      }
    }
  }
}

// ---------------- K3: flash attention, 8-wave blocks (128 q-rows) ------------
// Same per-wave math as r14; 2x q-rows per block halves K/V staging traffic
// and doubles compute per barrier at identical occupancy (2 blk/CU x 8 waves).
// Staging: 512 threads <-> exactly 512 16B chunks per 8KB tile (1 store each).
__global__ __launch_bounds__(512) void k3_attn(
    const _Float16* __restrict__ Qhi, const _Float16* __restrict__ Qlo,
    const _Float16* __restrict__ Khi, const _Float16* __restrict__ Klo,
    const unsigned short* __restrict__ Vt,
    unsigned short* __restrict__ AO)
{
  __shared__ __align__(16) _Float16 KhiL[64 * 64];
  __shared__ __align__(16) _Float16 KloL[64 * 64];
  __shared__ __align__(16) unsigned short VL[64 * 64];   // [f][m]
  __shared__ __align__(16) unsigned short PL[8][16 * 64];
  const int bh = blockIdx.x, qt = blockIdx.y;
  const int tid = threadIdx.x, wv = tid >> 6, lane = tid & 63;
  const int lrow = lane & 15, lgrp = lane >> 4;
  const size_t bhL = (size_t)bh * Lc;

  f16x8 qh[2], ql[2];
  {
    const int qrow = qt * 128 + wv * 16 + lrow;
    const _Float16* q1 = &Qhi[(bhL + qrow) * 64 + lgrp * 8];
    const _Float16* q2 = &Qlo[(bhL + qrow) * 64 + lgrp * 8];
    qh[0] = *(const f16x8*)q1; qh[1] = *(const f16x8*)(q1 + 32);
    ql[0] = *(const f16x8*)q2; ql[1] = *(const f16x8*)(q2 + 32);
  }

  f32x4 o[4] = {};
  float mrun = -1e30f, lrun = 0.f;       // lane-local: row q = lane&15

  const char* kbase = (const char*)(Khi + bhL * 64);
  const char* lbase = (const char*)(Klo + bhL * 64);
  const char* vbase = (const char*)(Vt + (size_t)bh * 64 * Lc);
  const int voff0 = (tid >> 3) * 2048 + (tid & 7) * 16;

  // prologue: issue tile 0 loads into staging regs (one chunk per thread)
  f16x8 ra0 = *(const f16x8*)(kbase + tid * 16);
  f16x8 rb0 = *(const f16x8*)(lbase + tid * 16);
  s16x8 rc0 = *(const s16x8*)(vbase + voff0);

  #pragma unroll 1
  for (int kt = 0; kt < 16; ++kt){
    __syncthreads();                       // prev tile's LDS consumers done
    *(f16x8*)((char*)KhiL + tid * 16) = ra0;
    *(f16x8*)((char*)KloL + tid * 16) = rb0;
    *(s16x8*)((char*)VL + tid * 16) = rc0;
    if (kt + 1 < 16){                      // issue NEXT tile now; lands under compute
      const char* kn = kbase + (kt + 1) * 8192;
      const char* ln = lbase + (kt + 1) * 8192;
      const char* vn = vbase + (kt + 1) * 128;
      ra0 = *(const f16x8*)(kn + tid * 16);
      rb0 = *(const f16x8*)(ln + tid * 16);
      rc0 = *(const s16x8*)(vn + voff0);
    }
    __syncthreads();                       // this tile's LDS ready

    // S^T = K.Q^T (swapped): lane holds S[q=lane&15][m = tt*16 + lgrp*4 + r]
    f32x4 s[4] = {};
    #pragma unroll
    for (int tt = 0; tt < 4; ++tt){
      #pragma unroll
      for (int ks = 0; ks < 2; ++ks){
        const int m = tt * 16 + lrow;
        const int off = m * 128 + swz(m, ks * 4 + lgrp) * 16;
        f16x8 kh_ = *(const f16x8*)((const char*)KhiL + off);
        f16x8 kl_ = *(const f16x8*)((const char*)KloL + off);
        s[tt] = __builtin_amdgcn_mfma_f32_16x16x32_f16(kh_, qh[ks], s[tt], 0, 0, 0);
        s[tt] = __builtin_amdgcn_mfma_f32_16x16x32_f16(kh_, ql[ks], s[tt], 0, 0, 0);
        s[tt] = __builtin_amdgcn_mfma_f32_16x16x32_f16(kl_, qh[ks], s[tt], 0, 0, 0);
      }
    }

    // online softmax: 16 in-reg values + 2 shfls (cross-lgrp)
    float v;
    {
      float v0 = fmaxf(fmaxf(s[0][0], s[0][1]), fmaxf(s[0][2], s[0][3]));
      float v1 = fmaxf(fmaxf(s[1][0], s[1][1]), fmaxf(s[1][2], s[1][3]));
      float v2 = fmaxf(fmaxf(s[2][0], s[2][1]), fmaxf(s[2][2], s[2][3]));
      float v3 = fmaxf(fmaxf(s[3][0], s[3][1]), fmaxf(s[3][2], s[3][3]));
      v = fmaxf(fmaxf(v0, v1), fmaxf(v2, v3));
      v = fmaxf(v, __shfl_xor(v, 16));
      v = fmaxf(v, __shfl_xor(v, 32));
    }
    const float mn = fmaxf(mrun, v);
    const float sc = __builtin_amdgcn_exp2f(mrun - mn);   // arg <= 0
    mrun = mn;

    float rs = 0.f;
    float pp[4][4];
    #pragma unroll
    for (int tt = 0; tt < 4; ++tt){
      #pragma unroll
      for (int r = 0; r < 4; ++r){
        const float p = __builtin_amdgcn_exp2f(s[tt][r] - mn);  // arg <= 0
        rs += p;
        pp[tt][r] = p;
      }
    }
    rs += __shfl_xor(rs, 16);
    rs += __shfl_xor(rs, 32);
    lrun = lrun * sc + rs;
    #pragma unroll
    for (int t2 = 0; t2 < 4; ++t2){
      o[t2][0] *= sc; o[t2][1] *= sc; o[t2][2] *= sc; o[t2][3] *= sc;
    }

    // P -> per-wave LDS: 4x ds_write_b64 (4 contiguous m per (tt)), cvt_pk packed
    short* pw = (short*)PL[wv];
    #pragma unroll
    for (int tt = 0; tt < 4; ++tt){
      uint2 pk;
      pk.x = cvtpk_bf16(pp[tt][0], pp[tt][1]);
      pk.y = cvtpk_bf16(pp[tt][2], pp[tt][3]);
      const int off = lrow * 128 + swz(lrow, tt * 2 + (lgrp >> 1)) * 16 + (lgrp & 1) * 8;
      *(uint2*)((char*)pw + off) = pk;
    }
    // HARD ORDER: mixed-width same-address LDS pair (rule #18 class hazard;
    // fixed r5's post-timing divergence).
    asm volatile("s_waitcnt lgkmcnt(0)" ::: "memory");
    __builtin_amdgcn_sched_barrier(0);

    // PV swapped: o = mfma(V, P) -> O^T[f][q]: cols = q = lane&15 (sc lane-local)
    #pragma unroll
    for (int ks = 0; ks < 2; ++ks){
      const int poff = lrow * 128 + swz(lrow, ks * 4 + lgrp) * 16;
      s16x8 pa = *(const s16x8*)((const char*)pw + poff);
      #pragma unroll
      for (int t2 = 0; t2 < 4; ++t2){
        const int f = t2 * 16 + lrow;
        const int voff = f * 128 + swz(f, ks * 4 + lgrp) * 16;
        s16x8 vb = *(const s16x8*)((const char*)VL + voff);
        o[t2] = __builtin_amdgcn_mfma_f32_16x16x32_bf16(vb, pa, o[t2], 0, 0, 0);
      }
    }
  }

  // epilogue: lane owns row l = qt*128 + wv*16 + (lane&15); f = t2*16 + lgrp*4 + r
  const int b = bh >> 4, hh = bh & 15;
  const float inv = 1.0f / lrun;
  const int l = qt * 128 + wv * 16 + lrow;
  unsigned short* aorow = &AO[((size_t)(b * Lc + l)) * DMc + hh * 64];
  #pragma unroll
  for (int t2 = 0; t2 < 4; ++t2){
    uint2 ov;
    ov.x = cvtpk_bf16(o[t2][0] * inv, o[t2][1] * inv);
    ov.y = cvtpk_bf16(o[t2][2] * inv, o[t2][3] * inv);
    *(uint2*)(aorow + t2 * 16 + lgrp * 4) = ov;
  }
}

// ---------------- K4: out = attn @ W_O^T + b  (bf16 MFMA GEMM, f32 out) ------
// grid (NBL/128, DM/128), block 256 (2x2 waves, each 64x64).
__global__ __launch_bounds__(256) void k4_out(
    const unsigned short* __restrict__ A, const unsigned short* __restrict__ Bw,
    const float* __restrict__ bias, float* __restrict__ out)
{
  __shared__ __align__(16) unsigned short Asl[128 * 64];
  __shared__ __align__(16) unsigned short Bsl[128 * 64];
  const int mt = blockIdx.x, nt = blockIdx.y;
  const int tid = threadIdx.x, wv = tid >> 6, lane = tid & 63;
  const int wr = wv >> 1, wc = wv & 1, lrow = lane & 15, lgrp = lane >> 4;
  f32x4 acc[4][4] = {};
  const char* abase = (const char*)A  + (size_t)mt * 128 * 2048;
  const char* bbase = (const char*)Bw + (size_t)nt * 128 * 2048;

  for (int kt = 0; kt < 16; ++kt){
    __syncthreads();
    #pragma unroll
    for (int q = 0; q < 4; ++q){
      const int i = q * 256 + tid, row = i >> 3, u = i & 7;
      s16x8 av = *(const s16x8*)(abase + (size_t)row * 2048 + kt * 128 + u * 16);
      s16x8 bv = *(const s16x8*)(bbase + (size_t)row * 2048 + kt * 128 + u * 16);
      *(s16x8*)((char*)Asl + row * 128 + swz(row, u) * 16) = av;
      *(s16x8*)((char*)Bsl + row * 128 + swz(row, u) * 16) = bv;
    }
    __syncthreads();
    #pragma unroll
    for (int ks = 0; ks < 2; ++ks){
      s16x8 af[4], bf[4];
      #pragma unroll
      for (int i4 = 0; i4 < 4; ++i4){
        const int row = wr * 64 + i4 * 16 + lrow;
        af[i4] = *(const s16x8*)((const char*)Asl + row * 128 + swz(row, ks * 4 + lgrp) * 16);
        const int col = wc * 64 + i4 * 16 + lrow;
        bf[i4] = *(const s16x8*)((const char*)Bsl + col * 128 + swz(col, ks * 4 + lgrp) * 16);
      }
      #pragma unroll
      for (int i4 = 0; i4 < 4; ++i4)
        #pragma unroll
        for (int j4 = 0; j4 < 4; ++j4)
          acc[i4][j4] = __builtin_amdgcn_mfma_f32_16x16x32_bf16(af[i4], bf[j4], acc[i4][j4], 0, 0, 0);
    }
  }
  #pragma unroll
  for (int i4 = 0; i4 < 4; ++i4)
    #pragma unroll
    for (int j4 = 0; j4 < 4; ++j4){
      const int col = nt * 128 + wc * 64 + j4 * 16 + lrow;
      const float bb = bias[col];
      #pragma unroll
      for (int r = 0; r < 4; ++r){
        const int row = mt * 128 + wr * 64 + i4 * 16 + lgrp * 4 + r;
        out[(size_t)row * DMc + col] = acc[i4][j4][r] + bb;
      }
    }
}

// ---------------- launch -----------------------------------------------------
extern "C" void kernel_launch(void* const* d_in, const int* in_sizes, int n_in,
                              void* d_out, int out_size, void* d_ws, size_t ws_size,
                              hipStream_t stream)
{
  const float* P   = (const float*)d_in[0];
  const float* t   = (const float*)d_in[1];
  const float* muQ = (const float*)d_in[2];
  const float* sgQ = (const float*)d_in[3];
  const float* wQ  = (const float*)d_in[4];
  const float* gQ  = (const float*)d_in[5];
  const float* WQ  = (const float*)d_in[6];
  const float* muK = (const float*)d_in[7];
  const float* sgK = (const float*)d_in[8];
  const float* wK  = (const float*)d_in[9];
  const float* gK  = (const float*)d_in[10];
  const float* WK  = (const float*)d_in[11];
  const float* muV = (const float*)d_in[12];
  const float* sgV = (const float*)d_in[13];
  const float* wV  = (const float*)d_in[14];
  const float* gV  = (const float*)d_in[15];
  const float* WV  = (const float*)d_in[16];
  const float* WO  = (const float*)d_in[17];
  const float* WOb = (const float*)d_in[18];

  char* w = (char*)d_ws;
  auto take = [&](size_t bytes) -> char* {
    char* p = w; w += (bytes + 255) & ~(size_t)255; return p;
  };
  float* PKb = (float*)take((size_t)3 * 3 * PAR * 4);
  float* GAb = (float*)take((size_t)3 * Hc * 64 * 4);
  float* OG  = (float*)take((size_t)3 * NBL * DMc * 4);   // Qg|Kg|Vg contiguous
  _Float16* Qhi = (_Float16*)take((size_t)NBL * DMc * 2);
  _Float16* Qlo = (_Float16*)take((size_t)NBL * DMc * 2);
  _Float16* Khi = (_Float16*)take((size_t)NBL * DMc * 2);
  _Float16* Klo = (_Float16*)take((size_t)NBL * DMc * 2);
  unsigned short* Vt    = (unsigned short*)take((size_t)NBL * DMc * 2);
  unsigned short* AO    = (unsigned short*)take((size_t)NBL * DMc * 2);
  unsigned short* WOb16 = (unsigned short*)take((size_t)DMc * DMc * 2);
  _Float16* Wsp_hi = (_Float16*)take((size_t)3 * Hc * 64 * 64 * 2);
  _Float16* Wsp_lo = (_Float16*)take((size_t)3 * Hc * 64 * 64 * 2);
  if ((size_t)(w - (char*)d_ws) > ws_size) return;  // insufficient scratch: bail

  float* Qg = OG;
  float* Kg = OG + (size_t)NBL * DMc;
  float* Vg = OG + (size_t)2 * NBL * DMc;

  k0_all<<<4096 + 768 + 768, 256, 0, stream>>>(
      muQ, sgQ, wQ, gQ, muK, sgK, wK, gK, muV, sgV, wV, gV,
      WQ, WK, WV, WO, PKb, GAb, Wsp_hi, Wsp_lo, WOb16);
  k1_gauss<<<dim3(Hc, NBL / 64, 3), 256, 0, stream>>>(P, t, PKb, GAb, OG);
  k2m<<<dim3(Hc, NBL / 64, 3), 256, 0, stream>>>(Qg, Kg, Vg, Wsp_hi, Wsp_lo,
      Qhi, Qlo, Khi, Klo, Vt);
  k3_attn<<<dim3(Bc * Hc, Lc / 128), 512, 0, stream>>>(Qhi, Qlo, Khi, Klo, Vt, AO);
  k4_out<<<dim3(NBL / 128, DMc / 128), 256, 0, stream>>>(AO, WOb16, WOb, (float*)d_out);
}